// Round 9
// baseline (418.508 us; speedup 1.0000x reference)
//
#include <hip/hip_runtime.h>
#include <hip/hip_bf16.h>
#include <hip/hip_fp16.h>
#include <math.h>

// Problem constants (fixed by setup_inputs)
#define D_MODEL   256
#define D_FFN     1024
#define N_LEVELS  4
#define N_HEADS   8
#define N_POINTS  4
#define BATCH     2
#define LQ        8192
#define S_TOTAL   21760            // 128*128 + 64*64 + 32*32 + 16*16
#define M_Q       (BATCH*LQ)       // 16384
#define M_V       (BATCH*S_TOTAL)  // 43520
#define VTILES    (M_V/128)        // 340

typedef __attribute__((ext_vector_type(8))) short bf16x8;   // 8 bf16 = 4 VGPRs
typedef __attribute__((ext_vector_type(4))) float floatx4;  // mfma C/D

struct alignas(8)  bh4 { __hip_bfloat16 a, b, c, d; };
struct alignas(16) bh8 { __hip_bfloat16 v[8]; };

__device__ __forceinline__ bf16x8 pack8(float4 a, float4 b) {
    bh8 o;
    o.v[0] = __float2bfloat16(a.x); o.v[1] = __float2bfloat16(a.y);
    o.v[2] = __float2bfloat16(a.z); o.v[3] = __float2bfloat16(a.w);
    o.v[4] = __float2bfloat16(b.x); o.v[5] = __float2bfloat16(b.y);
    o.v[6] = __float2bfloat16(b.z); o.v[7] = __float2bfloat16(b.w);
    return *(bf16x8*)&o;
}

// ---------------------------------------------------------------------------
// Direct-from-global MFMA GEMM core — NO LDS, NO barriers. Each lane loads
// its fragments straight from global per 32-wide K-tile:
//   a-frag: lane holds A[m = wrow + l15][k = kt + quad*8 + j]  (16B bf16, or
//           2x float4 + in-reg pack for f32 / f32-sum inputs)
//   b-frag: lane holds Bt[n = nb0 + ni*16 + l15][k = kt + quad*8 + j] (16B)
// Rationale: K is tiny (256/1024), so the LDS pipeline's per-iteration
// __syncthreads (s_waitcnt vmcnt(0)) drained every prefetch — all pipes idle
// (R8: MfmaUtil 5.5%, VALUBusy 8.8%). Without barriers the compiler pipelines
// loads across iterations with partial vmcnt waits; waves are independent.
// B re-reads across waves/blocks are served by L2/LLC (weights are hot).
// F32A: 0 = A bf16; 1 = A f32; 2 = A f32 + A2 f32 (elementwise sum).
// ---------------------------------------------------------------------------
template<int AF, int NT, int K, int F32A>
__device__ __forceinline__ void gemm_direct(const char* __restrict__ Ab,
                                            const float* __restrict__ A2,
                                            const __hip_bfloat16* __restrict__ Bt,
                                            int row0, int nb0, int lda, int ldb,
                                            floatx4 (&acc)[AF][NT])
{
    const int tid  = threadIdx.x;
    const int w    = tid >> 6;
    const int lane = tid & 63;
    const int quad = lane >> 4;
    const int l15  = lane & 15;

    const char* Ap[AF]; const float* A2p[AF];
#pragma unroll
    for (int mi = 0; mi < AF; mi++) {
        const int r = row0 + w * (AF * 16) + mi * 16 + l15;
        Ap[mi] = Ab + ((size_t)r * lda + quad * 8) * (F32A ? 4 : 2);
        A2p[mi] = (F32A == 2) ? (A2 + (size_t)r * lda + quad * 8) : nullptr;
    }
    const char* Bp[NT];
#pragma unroll
    for (int ni = 0; ni < NT; ni++)
        Bp[ni] = (const char*)(Bt + (size_t)(nb0 + ni * 16 + l15) * ldb + quad * 8);

#pragma unroll 8
    for (int it = 0; it < K / 32; ++it) {
        const int kt = it * 32;
        bf16x8 af[AF];
#pragma unroll
        for (int mi = 0; mi < AF; mi++) {
            if (F32A == 0) {
                af[mi] = *(const bf16x8*)(Ap[mi] + (size_t)kt * 2);
            } else {
                float4 f0 = *(const float4*)(Ap[mi] + (size_t)kt * 4);
                float4 f1 = *(const float4*)(Ap[mi] + (size_t)kt * 4 + 16);
                if (F32A == 2) {
                    float4 g0 = *(const float4*)(A2p[mi] + kt);
                    float4 g1 = *(const float4*)(A2p[mi] + kt + 4);
                    f0.x += g0.x; f0.y += g0.y; f0.z += g0.z; f0.w += g0.w;
                    f1.x += g1.x; f1.y += g1.y; f1.z += g1.z; f1.w += g1.w;
                }
                af[mi] = pack8(f0, f1);
            }
        }
        bf16x8 bfr[NT];
#pragma unroll
        for (int ni = 0; ni < NT; ni++)
            bfr[ni] = *(const bf16x8*)(Bp[ni] + (size_t)kt * 2);
#pragma unroll
        for (int ni = 0; ni < NT; ni++)
#pragma unroll
            for (int mi = 0; mi < AF; mi++)
                acc[mi][ni] = __builtin_amdgcn_mfma_f32_16x16x32_bf16(af[mi], bfr[ni], acc[mi][ni], 0, 0, 0);
    }
}

// ---------------------------------------------------------------------------
// Generic direct GEMM. Block = 4 waves x (AF*16) rows = AF*64 rows; cols
// nb0 = blockIdx.y * NT*16. EPI: 0 = f32 (+bias); 1 = bf16; 2 = relu->bf16.
// ---------------------------------------------------------------------------
template<int AF, int NT, int K, int EPI>
__global__ __launch_bounds__(256)
void mfma_gemm(const __hip_bfloat16* __restrict__ A,
               const __hip_bfloat16* __restrict__ Bt,
               const float* __restrict__ bias,
               float* __restrict__ outf, __hip_bfloat16* __restrict__ outb,
               int lda, int ldb, int ldOut)
{
    const int tid = threadIdx.x, w = tid >> 6, lane = tid & 63;
    const int quad = lane >> 4, l15 = lane & 15;
    const int row0 = blockIdx.x * (AF * 64), nb0 = blockIdx.y * (NT * 16);

    floatx4 acc[AF][NT];
#pragma unroll
    for (int mi = 0; mi < AF; mi++)
#pragma unroll
        for (int ni = 0; ni < NT; ni++) acc[mi][ni] = (floatx4){0.f, 0.f, 0.f, 0.f};

    gemm_direct<AF, NT, K, 0>((const char*)A, nullptr, Bt, row0, nb0, lda, ldb, acc);

    float bias_c[NT];
#pragma unroll
    for (int ni = 0; ni < NT; ni++) bias_c[ni] = bias ? bias[nb0 + ni * 16 + l15] : 0.f;

#pragma unroll
    for (int mi = 0; mi < AF; mi++)
#pragma unroll
        for (int r = 0; r < 4; r++) {
            int row = row0 + w * (AF * 16) + mi * 16 + quad * 4 + r;
            size_t rb = (size_t)row * ldOut + nb0;
#pragma unroll
            for (int ni = 0; ni < NT; ni++) {
                float v = acc[mi][ni][r] + bias_c[ni];
                if (EPI == 2)      outb[rb + ni * 16 + l15] = __float2bfloat16(fmaxf(v, 0.f));
                else if (EPI == 1) outb[rb + ni * 16 + l15] = __float2bfloat16(v);
                else               outf[rb + ni * 16 + l15] = v;
            }
        }
}

// ---------------------------------------------------------------------------
// Merged value-projection + off/attn GEMM (direct core, f32 A in-reg cvt).
// grid = (VTILES + 128, 3). x < VTILES: value = src @ Wv (y<2, bf16 out).
// x >= VTILES: (tgt+qpos) @ [W_off^T ++ W_attn^T] (y<2 off f32; y==2 softmax).
// ---------------------------------------------------------------------------
__global__ __launch_bounds__(256)
void mfma_gemm_vq(const float* __restrict__ src,
                  const __hip_bfloat16* __restrict__ Wvt,
                  const float* __restrict__ b_value,
                  __hip_bfloat16* __restrict__ valueb,
                  const float* __restrict__ tgt, const float* __restrict__ qpos,
                  const __hip_bfloat16* __restrict__ Woat,
                  const float* __restrict__ b_off, const float* __restrict__ b_attn,
                  float* __restrict__ offb, float* __restrict__ attnb)
{
    const bool isV = blockIdx.x < VTILES;
    if (isV && blockIdx.y == 2) return;

    const int tid = threadIdx.x, w = tid >> 6, lane = tid & 63;
    const int quad = lane >> 4, l15 = lane & 15;
    const int nb0 = blockIdx.y * 128;

    floatx4 acc[2][8];
#pragma unroll
    for (int mi = 0; mi < 2; mi++)
#pragma unroll
        for (int ni = 0; ni < 8; ni++) acc[mi][ni] = (floatx4){0.f, 0.f, 0.f, 0.f};

    if (isV) {
        const int row0 = blockIdx.x * 128;
        gemm_direct<2, 8, 256, 1>((const char*)src, nullptr, Wvt, row0, nb0, 256, 256, acc);
        float bias_c[8];
#pragma unroll
        for (int ni = 0; ni < 8; ni++) bias_c[ni] = b_value[nb0 + ni * 16 + l15];
#pragma unroll
        for (int mi = 0; mi < 2; mi++)
#pragma unroll
            for (int r = 0; r < 4; r++) {
                int row = row0 + w * 32 + mi * 16 + quad * 4 + r;
                size_t rb = (size_t)row * 256 + nb0;
#pragma unroll
                for (int ni = 0; ni < 8; ni++)
                    valueb[rb + ni * 16 + l15] = __float2bfloat16(acc[mi][ni][r] + bias_c[ni]);
            }
        return;
    }

    const int row0 = (blockIdx.x - VTILES) * 128;
    gemm_direct<2, 8, 256, 2>((const char*)tgt, qpos, Woat, row0, nb0, 256, 256, acc);

    if (blockIdx.y < 2) {    // offsets, f32, ld 256
        float bias_c[8];
#pragma unroll
        for (int ni = 0; ni < 8; ni++) bias_c[ni] = b_off[nb0 + ni * 16 + l15];
#pragma unroll
        for (int mi = 0; mi < 2; mi++)
#pragma unroll
            for (int r = 0; r < 4; r++) {
                int row = row0 + w * 32 + mi * 16 + quad * 4 + r;
                size_t rb = (size_t)row * 256 + nb0;
#pragma unroll
                for (int ni = 0; ni < 8; ni++)
                    offb[rb + ni * 16 + l15] = acc[mi][ni][r] + bias_c[ni];
            }
    } else {                 // attn: group-softmax(16) -> ld 128
        float bias_c[8];
#pragma unroll
        for (int ni = 0; ni < 8; ni++) bias_c[ni] = b_attn[ni * 16 + l15];
#pragma unroll
        for (int mi = 0; mi < 2; mi++)
#pragma unroll
            for (int r = 0; r < 4; r++) {
                int row = row0 + w * 32 + mi * 16 + quad * 4 + r;
                size_t rb = (size_t)row * 128;
#pragma unroll
                for (int ni = 0; ni < 8; ni++) {
                    float v = acc[mi][ni][r] + bias_c[ni];
                    float m = v;
#pragma unroll
                    for (int msk = 1; msk <= 8; msk <<= 1) m = fmaxf(m, __shfl_xor(m, msk));
                    float e = __expf(v - m);
                    float ssum = e;
#pragma unroll
                    for (int msk = 1; msk <= 8; msk <<= 1) ssum += __shfl_xor(ssum, msk);
                    attnb[rb + ni * 16 + l15] = e / ssum;
                }
            }
    }
}

// ---------------------------------------------------------------------------
// Residual + LayerNorm, one wave per 256-col row.
// ---------------------------------------------------------------------------
template<bool B1>
__global__ __launch_bounds__(256)
void ln_kernel(const float* __restrict__ in1f, const __hip_bfloat16* __restrict__ in1b,
               const float* __restrict__ resid, const float* __restrict__ bias,
               const float* __restrict__ g, const float* __restrict__ b,
               float* __restrict__ outf, __hip_bfloat16* __restrict__ outb)
{
    const int row  = blockIdx.x * 4 + (threadIdx.x >> 6);
    const int lane = threadIdx.x & 63;
    const size_t rb = (size_t)row * 256 + lane * 4;

    float4 v = *(const float4*)(resid + rb);
    if (B1) {
        bh4 a = *(const bh4*)(in1b + rb);
        v.x += __bfloat162float(a.a); v.y += __bfloat162float(a.b);
        v.z += __bfloat162float(a.c); v.w += __bfloat162float(a.d);
    } else {
        float4 a = *(const float4*)(in1f + rb);
        v.x += a.x; v.y += a.y; v.z += a.z; v.w += a.w;
    }
    if (bias) {
        float4 c = *(const float4*)(bias + lane * 4);
        v.x += c.x; v.y += c.y; v.z += c.z; v.w += c.w;
    }
    float s  = v.x + v.y + v.z + v.w;
    float sq = v.x * v.x + v.y * v.y + v.z * v.z + v.w * v.w;
#pragma unroll
    for (int msk = 1; msk <= 32; msk <<= 1) {
        s += __shfl_xor(s, msk); sq += __shfl_xor(sq, msk);
    }
    float mean = s * (1.f / 256.f);
    float var  = sq * (1.f / 256.f) - mean * mean;
    float rstd = rsqrtf(var + 1e-5f);
    float4 gg = *(const float4*)(g + lane * 4);
    float4 bb = *(const float4*)(b + lane * 4);
    float4 o;
    o.x = (v.x - mean) * rstd * gg.x + bb.x;
    o.y = (v.y - mean) * rstd * gg.y + bb.y;
    o.z = (v.z - mean) * rstd * gg.z + bb.z;
    o.w = (v.w - mean) * rstd * gg.w + bb.w;
    *(float4*)(outf + rb) = o;
    if (outb)
        *(bh4*)(outb + rb) = { __float2bfloat16(o.x), __float2bfloat16(o.y),
                               __float2bfloat16(o.z), __float2bfloat16(o.w) };
}

// ---------------------------------------------------------------------------
// Prep: weight transpose + f32->bf16 only (736 tiles of 32x32)
// ---------------------------------------------------------------------------
__global__ __launch_bounds__(256)
void prep_kernel(const float* w0, const float* w1, const float* w2,
                 const float* w3, const float* w4, const float* w5,
                 __hip_bfloat16* o0, __hip_bfloat16* o1, __hip_bfloat16* o2,
                 __hip_bfloat16* o3, __hip_bfloat16* o4, __hip_bfloat16* o5)
{
    int t = blockIdx.x;
    const float* s; __hip_bfloat16* dst; int Kd, Nd, tl;
    if      (t < 64)  { s = w0; dst = o0; Kd = 256;  Nd = 256;  tl = t; }
    else if (t < 128) { s = w1; dst = o1; Kd = 256;  Nd = 256;  tl = t - 64; }
    else if (t < 160) { s = w2; dst = o2; Kd = 256;  Nd = 128;  tl = t - 128; }
    else if (t < 224) { s = w3; dst = o3; Kd = 256;  Nd = 256;  tl = t - 160; }
    else if (t < 480) { s = w4; dst = o4; Kd = 256;  Nd = 1024; tl = t - 224; }
    else              { s = w5; dst = o5; Kd = 1024; Nd = 256;  tl = t - 480; }
    int ntn = Nd >> 5;
    int kt = tl / ntn, nt = tl - kt * ntn;
    __shared__ float T[32][33];
    int tx = threadIdx.x & 31, ty = threadIdx.x >> 5;
#pragma unroll
    for (int i = 0; i < 4; i++) {
        int k = kt * 32 + ty + i * 8;
        T[tx][ty + i * 8] = s[(size_t)k * Nd + nt * 32 + tx];
    }
    __syncthreads();
#pragma unroll
    for (int i = 0; i < 4; i++) {
        int n = nt * 32 + ty + i * 8;
        dst[(size_t)n * Kd + kt * 32 + tx] = __float2bfloat16(T[ty + i * 8][tx]);
    }
}

// ---------------------------------------------------------------------------
// Deformable bilinear sampling v5. Block = 8 queries, LDS 4B/entry
// ([31:16] pixel row, [15:0] weight fp16), stride-65 layout (conflict-free).
// Phase 2: thread=(ql,h,d4) gathers 8 channels per 16B load, explicit
// 16-deep load batching.
// ---------------------------------------------------------------------------
#define QB 8
__global__ __launch_bounds__(256, 4)
void sample_kernel(const float* __restrict__ refp, const float* __restrict__ offb,
                   const float* __restrict__ attn,
                   const __hip_bfloat16* __restrict__ value,
                   __hip_bfloat16* __restrict__ tgt2)
{
    __shared__ unsigned spk[64 * 65];       // [sc=lp*4+c][g=ql*8+h]

    const int q0  = blockIdx.x * QB;
    const int tid = threadIdx.x;

    // ---- phase 1 ----
#pragma unroll
    for (int k = 0; k < 4; k++) {
        const int it = tid + k * 256;        // (ql,h,lp)
        const int ql = it >> 7, h = (it >> 4) & 7, lp = it & 15;
        const int l = lp >> 2, p = lp & 3;
        const int q = q0 + ql, b = q >> 13;
        const int Wl = 128 >> l;
        const int LST = (l == 0) ? 0 : (l == 1) ? 16384 : (l == 2) ? 20480 : 21504;

        const float rx = refp[((size_t)q * N_LEVELS + l) * 2 + 0];
        const float ry = refp[((size_t)q * N_LEVELS + l) * 2 + 1];
        const float ox = offb[(size_t)q * 256 + h * 32 + l * 8 + p * 2 + 0];
        const float oy = offb[(size_t)q * 256 + h * 32 + l * 8 + p * 2 + 1];
        const float a  = attn[(size_t)q * 128 + h * 16 + lp];

        const float x = rx * Wl - 0.5f + ox;
        const float y = ry * Wl - 0.5f + oy;
        const float x0f = floorf(x), y0f = floorf(y);
        const float wx = x - x0f, wy = y - y0f;
        const int ix = (int)x0f, iy = (int)y0f;
        const int base = b * S_TOTAL + LST;
        const int g = ql * 8 + h;
        const float cw[4] = {(1.f - wx) * (1.f - wy) * a, wx * (1.f - wy) * a,
                             (1.f - wx) * wy * a,         wx * wy * a};
#pragma unroll
        for (int c = 0; c < 4; c++) {
            const int xi = ix + (c & 1), yi = iy + (c >> 1);
            const bool valid = ((unsigned)xi < (unsigned)Wl) && ((unsigned)yi < (unsigned)Wl);
            const unsigned pix = valid ? (unsigned)(base + yi * Wl + xi) : (unsigned)base;
            const __half hw = __float2half(valid ? cw[c] : 0.f);
            spk[(lp * 4 + c) * 65 + g] = (pix << 16) | (unsigned)__half_as_ushort(hw);
        }
    }
    __syncthreads();

    // ---- phase 2: 4 batches of 16 gathers, loads issued 16-deep ----
    const int ql = tid >> 5, h = (tid >> 2) & 7, d4 = tid & 3;
    const int q = q0 + ql, g = ql * 8 + h;
    const int c0 = h * 32 + d4 * 8;
    const char* vb = (const char*)value + (size_t)c0 * 2;

    float ac[8] = {0.f, 0.f, 0.f, 0.f, 0.f, 0.f, 0.f, 0.f};
#pragma unroll
    for (int ch = 0; ch < 4; ch++) {
        unsigned us[16];
#pragma unroll
        for (int j = 0; j < 16; j++) us[j] = spk[(ch * 16 + j) * 65 + g];
        uint4 rv[16];
#pragma unroll
        for (int j = 0; j < 16; j++)
            rv[j] = *(const uint4*)(vb + ((size_t)(us[j] >> 16) << 9));
#pragma unroll
        for (int j = 0; j < 16; j++) {
            float wv = __half2float(__ushort_as_half((unsigned short)(us[j] & 0xffffu)));
            ac[0] += wv * __uint_as_float(rv[j].x << 16);
            ac[1] += wv * __uint_as_float(rv[j].x & 0xffff0000u);
            ac[2] += wv * __uint_as_float(rv[j].y << 16);
            ac[3] += wv * __uint_as_float(rv[j].y & 0xffff0000u);
            ac[4] += wv * __uint_as_float(rv[j].z << 16);
            ac[5] += wv * __uint_as_float(rv[j].z & 0xffff0000u);
            ac[6] += wv * __uint_as_float(rv[j].w << 16);
            ac[7] += wv * __uint_as_float(rv[j].w & 0xffff0000u);
        }
    }
    bh8 o;
#pragma unroll
    for (int i = 0; i < 8; i++) o.v[i] = __float2bfloat16(ac[i]);
    *(bh8*)(tgt2 + (size_t)q * 256 + c0) = o;
}

// ---------------------------------------------------------------------------
extern "C" void kernel_launch(void* const* d_in, const int* in_sizes, int n_in,
                              void* d_out, int out_size, void* d_ws, size_t ws_size,
                              hipStream_t stream) {
    const float* tgt     = (const float*)d_in[0];
    const float* qpos    = (const float*)d_in[1];
    const float* refp    = (const float*)d_in[2];
    const float* src     = (const float*)d_in[3];
    const float* W_value = (const float*)d_in[6];
    const float* b_value = (const float*)d_in[7];
    const float* W_off   = (const float*)d_in[8];
    const float* b_off   = (const float*)d_in[9];
    const float* W_attn  = (const float*)d_in[10];
    const float* b_attn  = (const float*)d_in[11];
    const float* W_out   = (const float*)d_in[12];
    const float* b_out   = (const float*)d_in[13];
    const float* ln1_g   = (const float*)d_in[14];
    const float* ln1_b   = (const float*)d_in[15];
    const float* W1      = (const float*)d_in[16];
    const float* b1      = (const float*)d_in[17];
    const float* W2      = (const float*)d_in[18];
    const float* b2      = (const float*)d_in[19];
    const float* ln3_g   = (const float*)d_in[20];
    const float* ln3_b   = (const float*)d_in[21];
    float* out = (float*)d_out;

    // workspace layout
    char* p = (char*)d_ws;
    auto nxt = [&](size_t b) { char* r = p; p += (b + 255) & ~(size_t)255; return r; };
    __hip_bfloat16* Wvt    = (__hip_bfloat16*)nxt((size_t)256 * 256 * 2);
    __hip_bfloat16* Woat   = (__hip_bfloat16*)nxt((size_t)384 * 256 * 2);
    __hip_bfloat16* Woutt  = (__hip_bfloat16*)nxt((size_t)256 * 256 * 2);
    __hip_bfloat16* W1t    = (__hip_bfloat16*)nxt((size_t)1024 * 256 * 2);
    __hip_bfloat16* W2t    = (__hip_bfloat16*)nxt((size_t)256 * 1024 * 2);
    __hip_bfloat16* valueb = (__hip_bfloat16*)nxt((size_t)M_V * 256 * 2);  // dead after sampler
    float*          offb   = (float*)nxt((size_t)M_Q * 256 * 4);           // dead after sampler
    float*          attnb  = (float*)nxt((size_t)M_Q * 128 * 4);
    __hip_bfloat16* tgt2b  = (__hip_bfloat16*)nxt((size_t)M_Q * 256 * 2);
    __hip_bfloat16* t2ob   = (__hip_bfloat16*)nxt((size_t)M_Q * 256 * 2);
    float*          x      = (float*)nxt((size_t)M_Q * 256 * 4);
    __hip_bfloat16* xb     = (__hip_bfloat16*)nxt((size_t)M_Q * 256 * 2);
    __hip_bfloat16* hb     = (__hip_bfloat16*)nxt((size_t)M_Q * 1024 * 2);
    // FFN2 output (f32, 16.8 MB) overlays valueb (dead after sampler)
    float* f2o = (float*)valueb;

    dim3 blk(256);

    // 0) prep: weight transpose+cvt only
    prep_kernel<<<dim3(736), blk, 0, stream>>>(
        W_value, W_off, W_attn, W_out, W1, W2,
        Wvt, Woat, Woat + 256 * 256, Woutt, W1t, W2t);

    // 1) value GEMM ++ off/attn GEMM (direct, no-LDS core)
    mfma_gemm_vq<<<dim3(VTILES + M_Q / 128, 3), blk, 0, stream>>>(
        src, Wvt, b_value, valueb, tgt, qpos, Woat, b_off, b_attn, offb, attnb);

    // 2) deformable sampling -> tgt2 (bf16)
    sample_kernel<<<dim3(M_Q / QB), blk, 0, stream>>>(refp, offb, attnb, valueb, tgt2b);

    // 3) t2o = tgt2 @ W_out + b_out -> bf16  (AF=1 NT=4: 1024 blocks)
    mfma_gemm<1, 4, 256, 1><<<dim3(M_Q / 64, 4), blk, 0, stream>>>(
        tgt2b, Woutt, b_out, nullptr, t2ob, 256, 256, 256);

    // 4) x = LN1(tgt + t2o) -> f32 + bf16
    ln_kernel<true><<<dim3(M_Q / 4), blk, 0, stream>>>(
        nullptr, t2ob, tgt, nullptr, ln1_g, ln1_b, x, xb);

    // 5) h = relu(x @ W1 + b1) -> bf16  (AF=2 NT=8: 1024 blocks)
    mfma_gemm<2, 8, 256, 2><<<dim3(M_Q / 128, 8), blk, 0, stream>>>(
        xb, W1t, b1, nullptr, hb, 256, 256, 1024);

    // 6) f2o = h @ W2 + b2 -> f32, K=1024 (AF=1 NT=4: 1024 blocks)
    mfma_gemm<1, 4, 1024, 0><<<dim3(M_Q / 64, 4), blk, 0, stream>>>(
        hb, W2t, b2, f2o, nullptr, 1024, 1024, 256);

    // 7) out = LN3(x + f2o) -> f32
    ln_kernel<false><<<dim3(M_Q / 4), blk, 0, stream>>>(
        f2o, nullptr, x, nullptr, ln3_g, ln3_b, out, nullptr);
}

// Round 10
// 317.726 us; speedup vs baseline: 1.3172x; 1.3172x over previous
//
#include <hip/hip_runtime.h>
#include <hip/hip_bf16.h>
#include <hip/hip_fp16.h>
#include <math.h>

// Problem constants (fixed by setup_inputs)
#define D_MODEL   256
#define D_FFN     1024
#define N_LEVELS  4
#define N_HEADS   8
#define N_POINTS  4
#define BATCH     2
#define LQ        8192
#define S_TOTAL   21760            // 128*128 + 64*64 + 32*32 + 16*16
#define M_Q       (BATCH*LQ)       // 16384
#define M_V       (BATCH*S_TOTAL)  // 43520
#define VTILES    (M_V/128)        // 340

typedef __attribute__((ext_vector_type(8))) short bf16x8;   // 8 bf16 = 4 VGPRs
typedef __attribute__((ext_vector_type(4))) float floatx4;  // mfma C/D

struct alignas(8)  bh4 { __hip_bfloat16 a, b, c, d; };
struct alignas(16) bh8 { __hip_bfloat16 v[8]; };

__device__ __forceinline__ void gld_lds16(const void* g, void* l) {
    __builtin_amdgcn_global_load_lds(
        (const __attribute__((address_space(1))) void*)g,
        (__attribute__((address_space(3))) void*)l, 16, 0, 0);
}

__device__ __forceinline__ bf16x8 pack8(float4 a, float4 b) {
    bh8 o;
    o.v[0] = __float2bfloat16(a.x); o.v[1] = __float2bfloat16(a.y);
    o.v[2] = __float2bfloat16(a.z); o.v[3] = __float2bfloat16(a.w);
    o.v[4] = __float2bfloat16(b.x); o.v[5] = __float2bfloat16(b.y);
    o.v[6] = __float2bfloat16(b.z); o.v[7] = __float2bfloat16(b.w);
    return *(bf16x8*)&o;
}

// ---------------------------------------------------------------------------
// "Resident-B" MFMA GEMM core. The FULL Bt strip [BN=NT*16][K] bf16 is staged
// into LDS once (coalesced gld_lds16, ONE barrier), then the K-loop runs with
// ZERO barriers: A fragments stream direct from global (pipelined freely by
// the compiler — no vmcnt(0) drains), B fragments via ds_read_b128.
// Constraints learned R7-R9: (a) per-iter __syncthreads drains all vmem —
// kills thin-K GEMMs; (b) fragment-pattern global gathers are TA-bound;
// (c) staging must stay coalesced. This core satisfies all three.
// LDS swizzle: row r's 16B segment s stored at phys s^(r&7) (XOR within a
// 128B line, so staging lines are unchanged); read conflicts 16-way -> 8-way.
// F32A: 0 = A bf16; 1 = A f32; 2 = A f32 + A2 f32 (fused q=tgt+qpos).
// ---------------------------------------------------------------------------
template<int AF, int NT, int K, int F32A>
__device__ __forceinline__ void gemm_resB(const char* __restrict__ Ab,
                                          const float* __restrict__ A2,
                                          const char* __restrict__ BtW, // k-window base
                                          int row0, int nb0, int lda, int ldbB,
                                          short* Bs,
                                          floatx4 (&acc)[AF][NT])
{
    constexpr int S      = K / 8;                    // 16B segments per row
    constexpr int ROUNDS = (NT * 16 * K * 2) / 4096; // staging rounds

    const int tid  = threadIdx.x;
    const int w    = tid >> 6;
    const int lane = tid & 63;
    const int quad = lane >> 4;
    const int l15  = lane & 15;

    // ---- stage B strip (coalesced per 128B line, source-swizzled) ----
#pragma unroll
    for (int j = 0; j < ROUNDS; j++) {
        const int g = j * 256 + tid;          // global 16B-segment index
        const int r = g / S;                  // strip row
        const int p = g % S;                  // physical segment slot
        const int s = p ^ (r & 7);            // logical segment to fetch
        const char* src = BtW + (size_t)(nb0 + r) * ldbB + (s << 4);
        gld_lds16(src, Bs + ((size_t)j * 256 + w * 64) * 8);
    }
    __syncthreads();   // the ONLY barrier

    // ---- barrier-free K-loop ----
    const char* Ap[AF]; const float* A2p[AF];
#pragma unroll
    for (int mi = 0; mi < AF; mi++) {
        const int r = row0 + w * (AF * 16) + mi * 16 + l15;
        Ap[mi]  = Ab + ((size_t)r * lda + quad * 8) * (F32A ? 4 : 2);
        A2p[mi] = (F32A == 2) ? (A2 + (size_t)r * lda + quad * 8) : nullptr;
    }
    int rowK[NT];
#pragma unroll
    for (int ni = 0; ni < NT; ni++) rowK[ni] = (ni * 16 + l15) * K;
    const int swz = l15 & 7;

#pragma unroll
    for (int it = 0; it < K / 32; ++it) {
        bf16x8 af[AF];
#pragma unroll
        for (int mi = 0; mi < AF; mi++) {
            if (F32A == 0) {
                af[mi] = *(const bf16x8*)(Ap[mi] + (size_t)it * 64);
            } else {
                float4 f0 = *(const float4*)(Ap[mi] + (size_t)it * 128);
                float4 f1 = *(const float4*)(Ap[mi] + (size_t)it * 128 + 16);
                if (F32A == 2) {
                    float4 g0 = *(const float4*)(A2p[mi] + it * 32);
                    float4 g1 = *(const float4*)(A2p[mi] + it * 32 + 4);
                    f0.x += g0.x; f0.y += g0.y; f0.z += g0.z; f0.w += g0.w;
                    f1.x += g1.x; f1.y += g1.y; f1.z += g1.z; f1.w += g1.w;
                }
                af[mi] = pack8(f0, f1);
            }
        }
        const int seg = ((it * 4 + quad) ^ swz) << 3;   // shorts
#pragma unroll
        for (int ni = 0; ni < NT; ni++) {
            bf16x8 bfr = *(const bf16x8*)&Bs[rowK[ni] + seg];
#pragma unroll
            for (int mi = 0; mi < AF; mi++)
                acc[mi][ni] = __builtin_amdgcn_mfma_f32_16x16x32_bf16(af[mi], bfr, acc[mi][ni], 0, 0, 0);
        }
    }
}

// ---------------------------------------------------------------------------
// Generic resident-B GEMM. grid: x = COL tile (fastest -> A tile L2-reuse
// across col tiles), y = row tile, z = K-split (A/Bt advance z*K; f32 out
// advances z*zStride). EPI: 0 f32 (+bias); 1 bf16 (+bias); 2 relu->bf16.
// ---------------------------------------------------------------------------
template<int AF, int NT, int K, int EPI>
__global__ __launch_bounds__(256)
void mfma_gemm(const __hip_bfloat16* __restrict__ A,
               const __hip_bfloat16* __restrict__ Bt,
               const float* __restrict__ bias,
               float* __restrict__ outf, __hip_bfloat16* __restrict__ outb,
               int lda, int ldb, int ldOut, long zStride)
{
    __shared__ alignas(16) short Bs[NT * 16 * K];

    const int tid = threadIdx.x, w = tid >> 6, lane = tid & 63;
    const int quad = lane >> 4, l15 = lane & 15;
    const int nb0  = blockIdx.x * (NT * 16);
    const int row0 = blockIdx.y * (AF * 64);
    const int z    = blockIdx.z;

    floatx4 acc[AF][NT];
#pragma unroll
    for (int mi = 0; mi < AF; mi++)
#pragma unroll
        for (int ni = 0; ni < NT; ni++) acc[mi][ni] = (floatx4){0.f, 0.f, 0.f, 0.f};

    gemm_resB<AF, NT, K, 0>((const char*)A + (size_t)z * K * 2, nullptr,
                            (const char*)Bt + (size_t)z * K * 2,
                            row0, nb0, lda, ldb * 2, Bs, acc);

    float bias_c[NT];
#pragma unroll
    for (int ni = 0; ni < NT; ni++) bias_c[ni] = bias ? bias[nb0 + ni * 16 + l15] : 0.f;

    float* of = outf ? outf + (size_t)z * zStride : nullptr;
#pragma unroll
    for (int mi = 0; mi < AF; mi++)
#pragma unroll
        for (int r = 0; r < 4; r++) {
            int row = row0 + w * (AF * 16) + mi * 16 + quad * 4 + r;
            size_t rb = (size_t)row * ldOut + nb0;
#pragma unroll
            for (int ni = 0; ni < NT; ni++) {
                float v = acc[mi][ni][r] + bias_c[ni];
                if (EPI == 2)      outb[rb + ni * 16 + l15] = __float2bfloat16(fmaxf(v, 0.f));
                else if (EPI == 1) outb[rb + ni * 16 + l15] = __float2bfloat16(v);
                else               of[rb + ni * 16 + l15] = v;
            }
        }
}

// ---------------------------------------------------------------------------
// Merged value-projection + off/attn GEMM (resident-B, f32 A in-reg cvt).
// grid = (3, VTILES + 128): x = col tile (fastest -> A L2-reuse!).
// y < VTILES: value = src @ Wv (x<2, bf16 out; x==2 idle).
// y >= VTILES: (tgt+qpos) @ [W_off^T ++ W_attn^T] (x<2 off f32; x==2 softmax).
// ---------------------------------------------------------------------------
__global__ __launch_bounds__(256)
void mfma_gemm_vq(const float* __restrict__ src,
                  const __hip_bfloat16* __restrict__ Wvt,
                  const float* __restrict__ b_value,
                  __hip_bfloat16* __restrict__ valueb,
                  const float* __restrict__ tgt, const float* __restrict__ qpos,
                  const __hip_bfloat16* __restrict__ Woat,
                  const float* __restrict__ b_off, const float* __restrict__ b_attn,
                  float* __restrict__ offb, float* __restrict__ attnb)
{
    __shared__ alignas(16) short Bs[128 * 256];

    const int cx  = blockIdx.x;
    const bool isV = blockIdx.y < VTILES;
    if (isV && cx == 2) return;

    const int tid = threadIdx.x, w = tid >> 6, lane = tid & 63;
    const int quad = lane >> 4, l15 = lane & 15;
    const int nb0 = cx * 128;

    floatx4 acc[2][8];
#pragma unroll
    for (int mi = 0; mi < 2; mi++)
#pragma unroll
        for (int ni = 0; ni < 8; ni++) acc[mi][ni] = (floatx4){0.f, 0.f, 0.f, 0.f};

    if (isV) {
        const int row0 = blockIdx.y * 128;
        gemm_resB<2, 8, 256, 1>((const char*)src, nullptr, (const char*)Wvt,
                                row0, nb0, 256, 512, Bs, acc);
        float bias_c[8];
#pragma unroll
        for (int ni = 0; ni < 8; ni++) bias_c[ni] = b_value[nb0 + ni * 16 + l15];
#pragma unroll
        for (int mi = 0; mi < 2; mi++)
#pragma unroll
            for (int r = 0; r < 4; r++) {
                int row = row0 + w * 32 + mi * 16 + quad * 4 + r;
                size_t rb = (size_t)row * 256 + nb0;
#pragma unroll
                for (int ni = 0; ni < 8; ni++)
                    valueb[rb + ni * 16 + l15] = __float2bfloat16(acc[mi][ni][r] + bias_c[ni]);
            }
        return;
    }

    const int row0 = (blockIdx.y - VTILES) * 128;
    gemm_resB<2, 8, 256, 2>((const char*)tgt, qpos, (const char*)Woat,
                            row0, nb0, 256, 512, Bs, acc);

    if (cx < 2) {            // offsets, f32, ld 256
        float bias_c[8];
#pragma unroll
        for (int ni = 0; ni < 8; ni++) bias_c[ni] = b_off[nb0 + ni * 16 + l15];
#pragma unroll
        for (int mi = 0; mi < 2; mi++)
#pragma unroll
            for (int r = 0; r < 4; r++) {
                int row = row0 + w * 32 + mi * 16 + quad * 4 + r;
                size_t rb = (size_t)row * 256 + nb0;
#pragma unroll
                for (int ni = 0; ni < 8; ni++)
                    offb[rb + ni * 16 + l15] = acc[mi][ni][r] + bias_c[ni];
            }
    } else {                 // attn: group-softmax(16) -> ld 128
        float bias_c[8];
#pragma unroll
        for (int ni = 0; ni < 8; ni++) bias_c[ni] = b_attn[ni * 16 + l15];
#pragma unroll
        for (int mi = 0; mi < 2; mi++)
#pragma unroll
            for (int r = 0; r < 4; r++) {
                int row = row0 + w * 32 + mi * 16 + quad * 4 + r;
                size_t rb = (size_t)row * 128;
#pragma unroll
                for (int ni = 0; ni < 8; ni++) {
                    float v = acc[mi][ni][r] + bias_c[ni];
                    float m = v;
#pragma unroll
                    for (int msk = 1; msk <= 8; msk <<= 1) m = fmaxf(m, __shfl_xor(m, msk));
                    float e = __expf(v - m);
                    float ssum = e;
#pragma unroll
                    for (int msk = 1; msk <= 8; msk <<= 1) ssum += __shfl_xor(ssum, msk);
                    attnb[rb + ni * 16 + l15] = e / ssum;
                }
            }
    }
}

// ---------------------------------------------------------------------------
// Residual + LayerNorm, one wave per 256-col row.
// v = resid + in1 (+ in2) (+ bias). B1: in1 is bf16.
// ---------------------------------------------------------------------------
template<bool B1>
__global__ __launch_bounds__(256)
void ln_kernel(const float* __restrict__ in1f, const __hip_bfloat16* __restrict__ in1b,
               const float* __restrict__ in2,
               const float* __restrict__ resid, const float* __restrict__ bias,
               const float* __restrict__ g, const float* __restrict__ b,
               float* __restrict__ outf, __hip_bfloat16* __restrict__ outb)
{
    const int row  = blockIdx.x * 4 + (threadIdx.x >> 6);
    const int lane = threadIdx.x & 63;
    const size_t rb = (size_t)row * 256 + lane * 4;

    float4 v = *(const float4*)(resid + rb);
    if (B1) {
        bh4 a = *(const bh4*)(in1b + rb);
        v.x += __bfloat162float(a.a); v.y += __bfloat162float(a.b);
        v.z += __bfloat162float(a.c); v.w += __bfloat162float(a.d);
    } else {
        float4 a = *(const float4*)(in1f + rb);
        v.x += a.x; v.y += a.y; v.z += a.z; v.w += a.w;
    }
    if (in2) {
        float4 c = *(const float4*)(in2 + rb);
        v.x += c.x; v.y += c.y; v.z += c.z; v.w += c.w;
    }
    if (bias) {
        float4 c = *(const float4*)(bias + lane * 4);
        v.x += c.x; v.y += c.y; v.z += c.z; v.w += c.w;
    }
    float s  = v.x + v.y + v.z + v.w;
    float sq = v.x * v.x + v.y * v.y + v.z * v.z + v.w * v.w;
#pragma unroll
    for (int msk = 1; msk <= 32; msk <<= 1) {
        s += __shfl_xor(s, msk); sq += __shfl_xor(sq, msk);
    }
    float mean = s * (1.f / 256.f);
    float var  = sq * (1.f / 256.f) - mean * mean;
    float rstd = rsqrtf(var + 1e-5f);
    float4 gg = *(const float4*)(g + lane * 4);
    float4 bb = *(const float4*)(b + lane * 4);
    float4 o;
    o.x = (v.x - mean) * rstd * gg.x + bb.x;
    o.y = (v.y - mean) * rstd * gg.y + bb.y;
    o.z = (v.z - mean) * rstd * gg.z + bb.z;
    o.w = (v.w - mean) * rstd * gg.w + bb.w;
    *(float4*)(outf + rb) = o;
    if (outb)
        *(bh4*)(outb + rb) = { __float2bfloat16(o.x), __float2bfloat16(o.y),
                               __float2bfloat16(o.z), __float2bfloat16(o.w) };
}

// ---------------------------------------------------------------------------
// Prep: weight transpose + f32->bf16 only (736 tiles of 32x32)
// ---------------------------------------------------------------------------
__global__ __launch_bounds__(256)
void prep_kernel(const float* w0, const float* w1, const float* w2,
                 const float* w3, const float* w4, const float* w5,
                 __hip_bfloat16* o0, __hip_bfloat16* o1, __hip_bfloat16* o2,
                 __hip_bfloat16* o3, __hip_bfloat16* o4, __hip_bfloat16* o5)
{
    int t = blockIdx.x;
    const float* s; __hip_bfloat16* dst; int Kd, Nd, tl;
    if      (t < 64)  { s = w0; dst = o0; Kd = 256;  Nd = 256;  tl = t; }
    else if (t < 128) { s = w1; dst = o1; Kd = 256;  Nd = 256;  tl = t - 64; }
    else if (t < 160) { s = w2; dst = o2; Kd = 256;  Nd = 128;  tl = t - 128; }
    else if (t < 224) { s = w3; dst = o3; Kd = 256;  Nd = 256;  tl = t - 160; }
    else if (t < 480) { s = w4; dst = o4; Kd = 256;  Nd = 1024; tl = t - 224; }
    else              { s = w5; dst = o5; Kd = 1024; Nd = 256;  tl = t - 480; }
    int ntn = Nd >> 5;
    int kt = tl / ntn, nt = tl - kt * ntn;
    __shared__ float T[32][33];
    int tx = threadIdx.x & 31, ty = threadIdx.x >> 5;
#pragma unroll
    for (int i = 0; i < 4; i++) {
        int k = kt * 32 + ty + i * 8;
        T[tx][ty + i * 8] = s[(size_t)k * Nd + nt * 32 + tx];
    }
    __syncthreads();
#pragma unroll
    for (int i = 0; i < 4; i++) {
        int n = nt * 32 + ty + i * 8;
        dst[(size_t)n * Kd + kt * 32 + tx] = __float2bfloat16(T[ty + i * 8][tx]);
    }
}

// ---------------------------------------------------------------------------
// Deformable bilinear sampling (R8 version, 44.7 us). Block = 8 queries,
// LDS 4B/entry, stride-65, 16-deep batched 16B gathers.
// ---------------------------------------------------------------------------
#define QB 8
__global__ __launch_bounds__(256, 4)
void sample_kernel(const float* __restrict__ refp, const float* __restrict__ offb,
                   const float* __restrict__ attn,
                   const __hip_bfloat16* __restrict__ value,
                   __hip_bfloat16* __restrict__ tgt2)
{
    __shared__ unsigned spk[64 * 65];       // [sc=lp*4+c][g=ql*8+h]

    const int q0  = blockIdx.x * QB;
    const int tid = threadIdx.x;

#pragma unroll
    for (int k = 0; k < 4; k++) {
        const int it = tid + k * 256;        // (ql,h,lp)
        const int ql = it >> 7, h = (it >> 4) & 7, lp = it & 15;
        const int l = lp >> 2, p = lp & 3;
        const int q = q0 + ql, b = q >> 13;
        const int Wl = 128 >> l;
        const int LST = (l == 0) ? 0 : (l == 1) ? 16384 : (l == 2) ? 20480 : 21504;

        const float rx = refp[((size_t)q * N_LEVELS + l) * 2 + 0];
        const float ry = refp[((size_t)q * N_LEVELS + l) * 2 + 1];
        const float ox = offb[(size_t)q * 256 + h * 32 + l * 8 + p * 2 + 0];
        const float oy = offb[(size_t)q * 256 + h * 32 + l * 8 + p * 2 + 1];
        const float a  = attn[(size_t)q * 128 + h * 16 + lp];

        const float x = rx * Wl - 0.5f + ox;
        const float y = ry * Wl - 0.5f + oy;
        const float x0f = floorf(x), y0f = floorf(y);
        const float wx = x - x0f, wy = y - y0f;
        const int ix = (int)x0f, iy = (int)y0f;
        const int base = b * S_TOTAL + LST;
        const int g = ql * 8 + h;
        const float cw[4] = {(1.f - wx) * (1.f - wy) * a, wx * (1.f - wy) * a,
                             (1.f - wx) * wy * a,         wx * wy * a};
#pragma unroll
        for (int c = 0; c < 4; c++) {
            const int xi = ix + (c & 1), yi = iy + (c >> 1);
            const bool valid = ((unsigned)xi < (unsigned)Wl) && ((unsigned)yi < (unsigned)Wl);
            const unsigned pix = valid ? (unsigned)(base + yi * Wl + xi) : (unsigned)base;
            const __half hw = __float2half(valid ? cw[c] : 0.f);
            spk[(lp * 4 + c) * 65 + g] = (pix << 16) | (unsigned)__half_as_ushort(hw);
        }
    }
    __syncthreads();

    const int ql = tid >> 5, h = (tid >> 2) & 7, d4 = tid & 3;
    const int q = q0 + ql, g = ql * 8 + h;
    const int c0 = h * 32 + d4 * 8;
    const char* vb = (const char*)value + (size_t)c0 * 2;

    float ac[8] = {0.f, 0.f, 0.f, 0.f, 0.f, 0.f, 0.f, 0.f};
#pragma unroll
    for (int ch = 0; ch < 4; ch++) {
        unsigned us[16];
#pragma unroll
        for (int j = 0; j < 16; j++) us[j] = spk[(ch * 16 + j) * 65 + g];
        uint4 rv[16];
#pragma unroll
        for (int j = 0; j < 16; j++)
            rv[j] = *(const uint4*)(vb + ((size_t)(us[j] >> 16) << 9));
#pragma unroll
        for (int j = 0; j < 16; j++) {
            float wv = __half2float(__ushort_as_half((unsigned short)(us[j] & 0xffffu)));
            ac[0] += wv * __uint_as_float(rv[j].x << 16);
            ac[1] += wv * __uint_as_float(rv[j].x & 0xffff0000u);
            ac[2] += wv * __uint_as_float(rv[j].y << 16);
            ac[3] += wv * __uint_as_float(rv[j].y & 0xffff0000u);
            ac[4] += wv * __uint_as_float(rv[j].z << 16);
            ac[5] += wv * __uint_as_float(rv[j].z & 0xffff0000u);
            ac[6] += wv * __uint_as_float(rv[j].w << 16);
            ac[7] += wv * __uint_as_float(rv[j].w & 0xffff0000u);
        }
    }
    bh8 o;
#pragma unroll
    for (int i = 0; i < 8; i++) o.v[i] = __float2bfloat16(ac[i]);
    *(bh8*)(tgt2 + (size_t)q * 256 + c0) = o;
}

// ---------------------------------------------------------------------------
extern "C" void kernel_launch(void* const* d_in, const int* in_sizes, int n_in,
                              void* d_out, int out_size, void* d_ws, size_t ws_size,
                              hipStream_t stream) {
    const float* tgt     = (const float*)d_in[0];
    const float* qpos    = (const float*)d_in[1];
    const float* refp    = (const float*)d_in[2];
    const float* src     = (const float*)d_in[3];
    const float* W_value = (const float*)d_in[6];
    const float* b_value = (const float*)d_in[7];
    const float* W_off   = (const float*)d_in[8];
    const float* b_off   = (const float*)d_in[9];
    const float* W_attn  = (const float*)d_in[10];
    const float* b_attn  = (const float*)d_in[11];
    const float* W_out   = (const float*)d_in[12];
    const float* b_out   = (const float*)d_in[13];
    const float* ln1_g   = (const float*)d_in[14];
    const float* ln1_b   = (const float*)d_in[15];
    const float* W1      = (const float*)d_in[16];
    const float* b1      = (const float*)d_in[17];
    const float* W2      = (const float*)d_in[18];
    const float* b2      = (const float*)d_in[19];
    const float* ln3_g   = (const float*)d_in[20];
    const float* ln3_b   = (const float*)d_in[21];
    float* out = (float*)d_out;

    // workspace layout
    char* p = (char*)d_ws;
    auto nxt = [&](size_t b) { char* r = p; p += (b + 255) & ~(size_t)255; return r; };
    __hip_bfloat16* Wvt    = (__hip_bfloat16*)nxt((size_t)256 * 256 * 2);
    __hip_bfloat16* Woat   = (__hip_bfloat16*)nxt((size_t)384 * 256 * 2);
    __hip_bfloat16* Woutt  = (__hip_bfloat16*)nxt((size_t)256 * 256 * 2);
    __hip_bfloat16* W1t    = (__hip_bfloat16*)nxt((size_t)1024 * 256 * 2);
    __hip_bfloat16* W2t    = (__hip_bfloat16*)nxt((size_t)256 * 1024 * 2);
    __hip_bfloat16* valueb = (__hip_bfloat16*)nxt((size_t)M_V * 256 * 2);  // dead after sampler
    float*          offb   = (float*)nxt((size_t)M_Q * 256 * 4);           // dead after sampler
    float*          attnb  = (float*)nxt((size_t)M_Q * 128 * 4);
    __hip_bfloat16* tgt2b  = (__hip_bfloat16*)nxt((size_t)M_Q * 256 * 2);
    __hip_bfloat16* t2ob   = (__hip_bfloat16*)nxt((size_t)M_Q * 256 * 2);
    float*          x      = (float*)nxt((size_t)M_Q * 256 * 4);
    __hip_bfloat16* xb     = (__hip_bfloat16*)nxt((size_t)M_Q * 256 * 2);
    __hip_bfloat16* hb     = (__hip_bfloat16*)nxt((size_t)M_Q * 1024 * 2);
    // FFN2 split-K partials: contiguous 2 * M_Q*256 f32 (33.6 MB) overlaying
    // valueb (22.28 MB, 256B-aligned size -> offb directly follows) + offb —
    // both dead after the sampler. p1 = p0 + zStride exactly.
    float* p0 = (float*)valueb;
    float* p1 = p0 + (size_t)M_Q * 256;

    dim3 blk(256);

    // 0) prep: weight transpose+cvt only
    prep_kernel<<<dim3(736), blk, 0, stream>>>(
        W_value, W_off, W_attn, W_out, W1, W2,
        Wvt, Woat, Woat + 256 * 256, Woutt, W1t, W2t);

    // 1) value GEMM ++ off/attn GEMM (resident-B, col-tile-fastest grid)
    mfma_gemm_vq<<<dim3(3, VTILES + M_Q / 128), blk, 0, stream>>>(
        src, Wvt, b_value, valueb, tgt, qpos, Woat, b_off, b_attn, offb, attnb);

    // 2) deformable sampling -> tgt2 (bf16)
    sample_kernel<<<dim3(M_Q / QB), blk, 0, stream>>>(refp, offb, attnb, valueb, tgt2b);

    // 3) t2o = tgt2 @ W_out + b_out -> bf16   (BM=64, 512 blocks)
    mfma_gemm<1, 8, 256, 1><<<dim3(2, M_Q / 64), blk, 0, stream>>>(
        tgt2b, Woutt, b_out, nullptr, t2ob, 256, 256, 256, 0);

    // 4) x = LN1(tgt + t2o) -> f32 + bf16
    ln_kernel<true><<<dim3(M_Q / 4), blk, 0, stream>>>(
        nullptr, t2ob, nullptr, tgt, nullptr, ln1_g, ln1_b, x, xb);

    // 5) h = relu(x @ W1 + b1) -> bf16   (BM=128, 1024 blocks)
    mfma_gemm<2, 8, 256, 2><<<dim3(8, M_Q / 128), blk, 0, stream>>>(
        xb, W1t, b1, nullptr, hb, 256, 256, 1024, 0);

    // 6) FFN2 split-K x2: p[z] = h[:, z*512:+512] @ W2t[:, z*512:+512]
    //    (BM=64, BN=64, 2048 blocks)
    mfma_gemm<1, 4, 512, 0><<<dim3(4, M_Q / 64, 2), blk, 0, stream>>>(
        hb, W2t, nullptr, p0, nullptr, 1024, 1024, 256, (long)M_Q * 256);

    // 7) out = LN3(x + p0 + p1 + b2) -> f32
    ln_kernel<false><<<dim3(M_Q / 4), blk, 0, stream>>>(
        p0, nullptr, p1, x, b2, ln3_g, ln3_b, out, nullptr);
}

// Round 12
// 310.872 us; speedup vs baseline: 1.3462x; 1.0221x over previous
//
#include <hip/hip_runtime.h>
#include <hip/hip_bf16.h>
#include <hip/hip_fp16.h>
#include <math.h>

// Problem constants (fixed by setup_inputs)
#define D_MODEL   256
#define D_FFN     1024
#define N_LEVELS  4
#define N_HEADS   8
#define N_POINTS  4
#define BATCH     2
#define LQ        8192
#define S_TOTAL   21760            // 128*128 + 64*64 + 32*32 + 16*16
#define M_Q       (BATCH*LQ)       // 16384
#define M_V       (BATCH*S_TOTAL)  // 43520
#define VT64      (M_V/64)         // 680 row tiles for value GEMM

typedef __attribute__((ext_vector_type(8))) short bf16x8;   // 8 bf16 = 4 VGPRs
typedef __attribute__((ext_vector_type(4))) float floatx4;  // mfma C/D

struct alignas(8)  bh4 { __hip_bfloat16 a, b, c, d; };
struct alignas(16) bh8 { __hip_bfloat16 v[8]; };

__device__ __forceinline__ void gld_lds16(const void* g, void* l) {
    __builtin_amdgcn_global_load_lds(
        (const __attribute__((address_space(1))) void*)g,
        (__attribute__((address_space(3))) void*)l, 16, 0, 0);
}

__device__ __forceinline__ bh4 pack4(float4 a) {
    return { __float2bfloat16(a.x), __float2bfloat16(a.y),
             __float2bfloat16(a.z), __float2bfloat16(a.w) };
}

// ---------------------------------------------------------------------------
// 64x64 bf16 MFMA core, double-buffered LDS, one barrier/K-iter. 4 waves,
// each computing 16 rows x 64 cols (AF=1, NT=4). LDS = 2x(4KB A + 4KB B) =
// 16 KB -> 5-6 blocks/CU resident (vs 2-3 at 128-tile): the residency is the
// point — with K=256 a block has ~1 us of work, and barrier-drain stalls can
// only be hidden by OTHER resident blocks (R7-R10: 128-tiles pinned at
// occupancy 13-15%, MfmaUtil 5%, regardless of staging style).
// ---------------------------------------------------------------------------
template<int K>
__device__ __forceinline__ void gemm_core64(const __hip_bfloat16* __restrict__ A,
                                            const __hip_bfloat16* __restrict__ Bt,
                                            int row0, int nb0, int lda, int ldb,
                                            short* As, short* Bs, floatx4 (&acc)[4])
{
    constexpr int NIT = K / 32;
    const int tid  = threadIdx.x;
    const int w    = tid >> 6;
    const int lane = tid & 63;
    const int quad = lane >> 4;
    const int l15  = lane & 15;
    const size_t ldaB = (size_t)lda * 2, ldbB = (size_t)ldb * 2;

    const int o = w * 1024 + lane * 16;          // byte offset in 4KB tile
    const char* gA = (const char*)A + (size_t)(row0 + (o >> 6)) * ldaB + (o & 63);
    const char* gB = (const char*)Bt + (size_t)(nb0 + (o >> 6)) * ldbB + (o & 63);
    const int lofs = w * 512;                    // shorts

    gld_lds16(gA, As + lofs);
    gld_lds16(gB, Bs + lofs);

#pragma unroll 8
    for (int it = 0; it < NIT; ++it) {
        __syncthreads();
        const int cb = it & 1;
        if (it + 1 < NIT) {
            const size_t kb = (size_t)(it + 1) * 64;   // 32 k * 2 B
            gld_lds16(gA + kb, As + (cb ^ 1) * 2048 + lofs);
            gld_lds16(gB + kb, Bs + (cb ^ 1) * 2048 + lofs);
        }
        const short* Ab = As + cb * 2048;
        const short* Bb = Bs + cb * 2048;
        bf16x8 af = *(const bf16x8*)&Ab[(w * 16 + l15) * 32 + quad * 8];
#pragma unroll
        for (int ni = 0; ni < 4; ni++) {
            bf16x8 bfr = *(const bf16x8*)&Bb[(ni * 16 + l15) * 32 + quad * 8];
            acc[ni] = __builtin_amdgcn_mfma_f32_16x16x32_bf16(af, bfr, acc[ni], 0, 0, 0);
        }
    }
}

// ---------------------------------------------------------------------------
// 64x64 core with f32 A (optionally A+A2), converted to bf16 during staging.
// A staging is COALESCED (R8 lesson): thread covers 16B f32 segments of the
// 8KB tile -> row tid/8, k-bytes (tid&7)*16; 8 consecutive lanes cover a full
// 128B row. Pack -> 8B ds_write (sequential, conflict-free). B via gld_lds16.
// ---------------------------------------------------------------------------
template<int K, bool ADD>
__device__ __forceinline__ void gemm_core_cvt64(const float* __restrict__ Af,
                                                const float* __restrict__ A2f,
                                                const __hip_bfloat16* __restrict__ Bt,
                                                int row0, int nb0, int lda, int ldb,
                                                short* As, short* Bs, floatx4 (&acc)[4])
{
    constexpr int NIT = K / 32;
    const int tid  = threadIdx.x;
    const int w    = tid >> 6;
    const int lane = tid & 63;
    const int quad = lane >> 4;
    const int l15  = lane & 15;

    const int o = w * 1024 + lane * 16;
    const char* gB = (const char*)Bt + (size_t)(nb0 + (o >> 6)) * ((size_t)ldb * 2) + (o & 63);
    const int lofs = w * 512;

    const int r0 = tid >> 3, k0 = (tid & 7) * 4;     // f32 index
    const float* gA0 = Af + (size_t)(row0 + r0) * lda + k0;        // rows 0..31
    const float* gA1 = gA0 + (size_t)32 * lda;                     // rows 32..63
    const float* gB0 = ADD ? (A2f + (size_t)(row0 + r0) * lda + k0) : nullptr;
    const float* gB1 = ADD ? (gB0 + (size_t)32 * lda) : nullptr;
    const int aofs0 = r0 * 32 + k0, aofs1 = aofs0 + 1024;

    float4 f0, f1;
    auto loadA = [&](int kt) {
        f0 = *(const float4*)(gA0 + kt);
        f1 = *(const float4*)(gA1 + kt);
        if (ADD) {
            float4 a = *(const float4*)(gB0 + kt);
            float4 b = *(const float4*)(gB1 + kt);
            f0.x += a.x; f0.y += a.y; f0.z += a.z; f0.w += a.w;
            f1.x += b.x; f1.y += b.y; f1.z += b.z; f1.w += b.w;
        }
    };
    auto writeA = [&](short* buf) {
        *(bh4*)&buf[aofs0] = pack4(f0);
        *(bh4*)&buf[aofs1] = pack4(f1);
    };

    loadA(0);
    gld_lds16(gB, Bs + lofs);
    writeA(As);

#pragma unroll 8
    for (int it = 0; it < NIT; ++it) {
        __syncthreads();
        const int cb = it & 1;
        const bool more = (it + 1 < NIT);
        if (more) {
            loadA((it + 1) * 32);
            gld_lds16(gB + (size_t)(it + 1) * 64, Bs + (cb ^ 1) * 2048 + lofs);
        }
        const short* Ab = As + cb * 2048;
        const short* Bb = Bs + cb * 2048;
        bf16x8 af = *(const bf16x8*)&Ab[(w * 16 + l15) * 32 + quad * 8];
#pragma unroll
        for (int ni = 0; ni < 4; ni++) {
            bf16x8 bfr = *(const bf16x8*)&Bb[(ni * 16 + l15) * 32 + quad * 8];
            acc[ni] = __builtin_amdgcn_mfma_f32_16x16x32_bf16(af, bfr, acc[ni], 0, 0, 0);
        }
        if (more) writeA(As + (cb ^ 1) * 2048);
    }
}

// ---------------------------------------------------------------------------
// Generic 64x64 GEMM, bf16 A. grid: x = COL tile (fastest -> A/B L2 reuse),
// y = row tile. EPI: 0 f32 (+bias); 1 bf16 (+bias); 2 relu -> bf16.
// ---------------------------------------------------------------------------
template<int K, int EPI>
__global__ __launch_bounds__(256)
void mfma_gemm64(const __hip_bfloat16* __restrict__ A,
                 const __hip_bfloat16* __restrict__ Bt,
                 const float* __restrict__ bias,
                 float* __restrict__ outf, __hip_bfloat16* __restrict__ outb,
                 int lda, int ldb, int ldOut)
{
    __shared__ alignas(16) short As[2 * 2048];
    __shared__ alignas(16) short Bs[2 * 2048];

    const int tid = threadIdx.x, w = tid >> 6, lane = tid & 63;
    const int quad = lane >> 4, l15 = lane & 15;
    const int nb0  = blockIdx.x * 64;
    const int row0 = blockIdx.y * 64;

    floatx4 acc[4];
#pragma unroll
    for (int ni = 0; ni < 4; ni++) acc[ni] = (floatx4){0.f, 0.f, 0.f, 0.f};

    gemm_core64<K>(A, Bt, row0, nb0, lda, ldb, As, Bs, acc);

    float bias_c[4];
#pragma unroll
    for (int ni = 0; ni < 4; ni++) bias_c[ni] = bias ? bias[nb0 + ni * 16 + l15] : 0.f;

#pragma unroll
    for (int r = 0; r < 4; r++) {
        int row = row0 + w * 16 + quad * 4 + r;
        size_t rb = (size_t)row * ldOut + nb0;
#pragma unroll
        for (int ni = 0; ni < 4; ni++) {
            float v = acc[ni][r] + bias_c[ni];
            if (EPI == 2)      outb[rb + ni * 16 + l15] = __float2bfloat16(fmaxf(v, 0.f));
            else if (EPI == 1) outb[rb + ni * 16 + l15] = __float2bfloat16(v);
            else               outf[rb + ni * 16 + l15] = v;
        }
    }
}

// ---------------------------------------------------------------------------
// Merged value-projection + off/attn GEMM (64x64, fused f32 cvt staging).
// grid = (6, 680+256), x = col tile (fastest).
// y < 680: value = src @ Wv (x<4; x>=4 early-exit).
// y >= 680: q = tgt+qpos vs Woat: x<4 -> off (cols x*64, f32 ld 256);
//           x>=4 -> attn (Woat rows 256+(x-4)*64, softmax16 -> ld 128).
// ---------------------------------------------------------------------------
__global__ __launch_bounds__(256)
void mfma_gemm_vq(const float* __restrict__ src,
                  const __hip_bfloat16* __restrict__ Wvt,
                  const float* __restrict__ b_value,
                  __hip_bfloat16* __restrict__ valueb,
                  const float* __restrict__ tgt, const float* __restrict__ qpos,
                  const __hip_bfloat16* __restrict__ Woat,
                  const float* __restrict__ b_off, const float* __restrict__ b_attn,
                  float* __restrict__ offb, float* __restrict__ attnb)
{
    __shared__ alignas(16) short As[2 * 2048];
    __shared__ alignas(16) short Bs[2 * 2048];

    const int cx = blockIdx.x;
    const bool isV = blockIdx.y < VT64;
    if (isV && cx >= 4) return;

    const int tid = threadIdx.x, w = tid >> 6, lane = tid & 63;
    const int quad = lane >> 4, l15 = lane & 15;

    floatx4 acc[4];
#pragma unroll
    for (int ni = 0; ni < 4; ni++) acc[ni] = (floatx4){0.f, 0.f, 0.f, 0.f};

    if (isV) {
        const int row0 = blockIdx.y * 64, nb0 = cx * 64;
        gemm_core_cvt64<256, false>(src, nullptr, Wvt, row0, nb0, 256, 256, As, Bs, acc);
        float bias_c[4];
#pragma unroll
        for (int ni = 0; ni < 4; ni++) bias_c[ni] = b_value[nb0 + ni * 16 + l15];
#pragma unroll
        for (int r = 0; r < 4; r++) {
            int row = row0 + w * 16 + quad * 4 + r;
            size_t rb = (size_t)row * 256 + nb0;
#pragma unroll
            for (int ni = 0; ni < 4; ni++)
                valueb[rb + ni * 16 + l15] = __float2bfloat16(acc[ni][r] + bias_c[ni]);
        }
        return;
    }

    const int row0 = (blockIdx.y - VT64) * 64;
    if (cx < 4) {            // offsets: cols cx*64 of Woat, f32 out ld 256
        const int nb0 = cx * 64;
        gemm_core_cvt64<256, true>(tgt, qpos, Woat, row0, nb0, 256, 256, As, Bs, acc);
        float bias_c[4];
#pragma unroll
        for (int ni = 0; ni < 4; ni++) bias_c[ni] = b_off[nb0 + ni * 16 + l15];
#pragma unroll
        for (int r = 0; r < 4; r++) {
            int row = row0 + w * 16 + quad * 4 + r;
            size_t rb = (size_t)row * 256 + nb0;
#pragma unroll
            for (int ni = 0; ni < 4; ni++)
                offb[rb + ni * 16 + l15] = acc[ni][r] + bias_c[ni];
        }
    } else {                 // attn: Woat rows 256 + (cx-4)*64; softmax16
        const int c0 = (cx - 4) * 64;
        gemm_core_cvt64<256, true>(tgt, qpos, Woat, row0, 256 + c0, 256, 256, As, Bs, acc);
        float bias_c[4];
#pragma unroll
        for (int ni = 0; ni < 4; ni++) bias_c[ni] = b_attn[c0 + ni * 16 + l15];
#pragma unroll
        for (int r = 0; r < 4; r++) {
            int row = row0 + w * 16 + quad * 4 + r;
            size_t rb = (size_t)row * 128 + c0;
#pragma unroll
            for (int ni = 0; ni < 4; ni++) {
                float v = acc[ni][r] + bias_c[ni];
                float m = v;
#pragma unroll
                for (int msk = 1; msk <= 8; msk <<= 1) m = fmaxf(m, __shfl_xor(m, msk));
                float e = __expf(v - m);
                float ssum = e;
#pragma unroll
                for (int msk = 1; msk <= 8; msk <<= 1) ssum += __shfl_xor(ssum, msk);
                attnb[rb + ni * 16 + l15] = e / ssum;
            }
        }
    }
}

// ---------------------------------------------------------------------------
// Residual + LayerNorm, one wave per 256-col row.
// v = resid + in1 (+ in2) (+ bias). B1: in1 is bf16.
// ---------------------------------------------------------------------------
template<bool B1>
__global__ __launch_bounds__(256)
void ln_kernel(const float* __restrict__ in1f, const __hip_bfloat16* __restrict__ in1b,
               const float* __restrict__ in2,
               const float* __restrict__ resid, const float* __restrict__ bias,
               const float* __restrict__ g, const float* __restrict__ b,
               float* __restrict__ outf, __hip_bfloat16* __restrict__ outb)
{
    const int row  = blockIdx.x * 4 + (threadIdx.x >> 6);
    const int lane = threadIdx.x & 63;
    const size_t rb = (size_t)row * 256 + lane * 4;

    float4 v = *(const float4*)(resid + rb);
    if (B1) {
        bh4 a = *(const bh4*)(in1b + rb);
        v.x += __bfloat162float(a.a); v.y += __bfloat162float(a.b);
        v.z += __bfloat162float(a.c); v.w += __bfloat162float(a.d);
    } else {
        float4 a = *(const float4*)(in1f + rb);
        v.x += a.x; v.y += a.y; v.z += a.z; v.w += a.w;
    }
    if (in2) {
        float4 c = *(const float4*)(in2 + rb);
        v.x += c.x; v.y += c.y; v.z += c.z; v.w += c.w;
    }
    if (bias) {
        float4 c = *(const float4*)(bias + lane * 4);
        v.x += c.x; v.y += c.y; v.z += c.z; v.w += c.w;
    }
    float s  = v.x + v.y + v.z + v.w;
    float sq = v.x * v.x + v.y * v.y + v.z * v.z + v.w * v.w;
#pragma unroll
    for (int msk = 1; msk <= 32; msk <<= 1) {
        s += __shfl_xor(s, msk); sq += __shfl_xor(sq, msk);
    }
    float mean = s * (1.f / 256.f);
    float var  = sq * (1.f / 256.f) - mean * mean;
    float rstd = rsqrtf(var + 1e-5f);
    float4 gg = *(const float4*)(g + lane * 4);
    float4 bb = *(const float4*)(b + lane * 4);
    float4 o;
    o.x = (v.x - mean) * rstd * gg.x + bb.x;
    o.y = (v.y - mean) * rstd * gg.y + bb.y;
    o.z = (v.z - mean) * rstd * gg.z + bb.z;
    o.w = (v.w - mean) * rstd * gg.w + bb.w;
    *(float4*)(outf + rb) = o;
    if (outb)
        *(bh4*)(outb + rb) = { __float2bfloat16(o.x), __float2bfloat16(o.y),
                               __float2bfloat16(o.z), __float2bfloat16(o.w) };
}

// ---------------------------------------------------------------------------
// Prep: weight transpose + f32->bf16 only (736 tiles of 32x32)
// ---------------------------------------------------------------------------
__global__ __launch_bounds__(256)
void prep_kernel(const float* w0, const float* w1, const float* w2,
                 const float* w3, const float* w4, const float* w5,
                 __hip_bfloat16* o0, __hip_bfloat16* o1, __hip_bfloat16* o2,
                 __hip_bfloat16* o3, __hip_bfloat16* o4, __hip_bfloat16* o5)
{
    int t = blockIdx.x;
    const float* s; __hip_bfloat16* dst; int Kd, Nd, tl;
    if      (t < 64)  { s = w0; dst = o0; Kd = 256;  Nd = 256;  tl = t; }
    else if (t < 128) { s = w1; dst = o1; Kd = 256;  Nd = 256;  tl = t - 64; }
    else if (t < 160) { s = w2; dst = o2; Kd = 256;  Nd = 128;  tl = t - 128; }
    else if (t < 224) { s = w3; dst = o3; Kd = 256;  Nd = 256;  tl = t - 160; }
    else if (t < 480) { s = w4; dst = o4; Kd = 256;  Nd = 1024; tl = t - 224; }
    else              { s = w5; dst = o5; Kd = 1024; Nd = 256;  tl = t - 480; }
    int ntn = Nd >> 5;
    int kt = tl / ntn, nt = tl - kt * ntn;
    __shared__ float T[32][33];
    int tx = threadIdx.x & 31, ty = threadIdx.x >> 5;
#pragma unroll
    for (int i = 0; i < 4; i++) {
        int k = kt * 32 + ty + i * 8;
        T[tx][ty + i * 8] = s[(size_t)k * Nd + nt * 32 + tx];
    }
    __syncthreads();
#pragma unroll
    for (int i = 0; i < 4; i++) {
        int n = nt * 32 + ty + i * 8;
        dst[(size_t)n * Kd + kt * 32 + tx] = __float2bfloat16(T[ty + i * 8][tx]);
    }
}

// ---------------------------------------------------------------------------
// Deformable bilinear sampling (R8 version, 44.7 us best). Block = 8 queries,
// LDS 4B/entry, stride-65, 16-deep batched 16B gathers.
// ---------------------------------------------------------------------------
#define QB 8
__global__ __launch_bounds__(256, 4)
void sample_kernel(const float* __restrict__ refp, const float* __restrict__ offb,
                   const float* __restrict__ attn,
                   const __hip_bfloat16* __restrict__ value,
                   __hip_bfloat16* __restrict__ tgt2)
{
    __shared__ unsigned spk[64 * 65];       // [sc=lp*4+c][g=ql*8+h]

    const int q0  = blockIdx.x * QB;
    const int tid = threadIdx.x;

#pragma unroll
    for (int k = 0; k < 4; k++) {
        const int it = tid + k * 256;        // (ql,h,lp)
        const int ql = it >> 7, h = (it >> 4) & 7, lp = it & 15;
        const int l = lp >> 2, p = lp & 3;
        const int q = q0 + ql, b = q >> 13;
        const int Wl = 128 >> l;
        const int LST = (l == 0) ? 0 : (l == 1) ? 16384 : (l == 2) ? 20480 : 21504;

        const float rx = refp[((size_t)q * N_LEVELS + l) * 2 + 0];
        const float ry = refp[((size_t)q * N_LEVELS + l) * 2 + 1];
        const float ox = offb[(size_t)q * 256 + h * 32 + l * 8 + p * 2 + 0];
        const float oy = offb[(size_t)q * 256 + h * 32 + l * 8 + p * 2 + 1];
        const float a  = attn[(size_t)q * 128 + h * 16 + lp];

        const float x = rx * Wl - 0.5f + ox;
        const float y = ry * Wl - 0.5f + oy;
        const float x0f = floorf(x), y0f = floorf(y);
        const float wx = x - x0f, wy = y - y0f;
        const int ix = (int)x0f, iy = (int)y0f;
        const int base = b * S_TOTAL + LST;
        const int g = ql * 8 + h;
        const float cw[4] = {(1.f - wx) * (1.f - wy) * a, wx * (1.f - wy) * a,
                             (1.f - wx) * wy * a,         wx * wy * a};
#pragma unroll
        for (int c = 0; c < 4; c++) {
            const int xi = ix + (c & 1), yi = iy + (c >> 1);
            const bool valid = ((unsigned)xi < (unsigned)Wl) && ((unsigned)yi < (unsigned)Wl);
            const unsigned pix = valid ? (unsigned)(base + yi * Wl + xi) : (unsigned)base;
            const __half hw = __float2half(valid ? cw[c] : 0.f);
            spk[(lp * 4 + c) * 65 + g] = (pix << 16) | (unsigned)__half_as_ushort(hw);
        }
    }
    __syncthreads();

    const int ql = tid >> 5, h = (tid >> 2) & 7, d4 = tid & 3;
    const int q = q0 + ql, g = ql * 8 + h;
    const int c0 = h * 32 + d4 * 8;
    const char* vb = (const char*)value + (size_t)c0 * 2;

    float ac[8] = {0.f, 0.f, 0.f, 0.f, 0.f, 0.f, 0.f, 0.f};
#pragma unroll
    for (int ch = 0; ch < 4; ch++) {
        unsigned us[16];
#pragma unroll
        for (int j = 0; j < 16; j++) us[j] = spk[(ch * 16 + j) * 65 + g];
        uint4 rv[16];
#pragma unroll
        for (int j = 0; j < 16; j++)
            rv[j] = *(const uint4*)(vb + ((size_t)(us[j] >> 16) << 9));
#pragma unroll
        for (int j = 0; j < 16; j++) {
            float wv = __half2float(__ushort_as_half((unsigned short)(us[j] & 0xffffu)));
            ac[0] += wv * __uint_as_float(rv[j].x << 16);
            ac[1] += wv * __uint_as_float(rv[j].x & 0xffff0000u);
            ac[2] += wv * __uint_as_float(rv[j].y << 16);
            ac[3] += wv * __uint_as_float(rv[j].y & 0xffff0000u);
            ac[4] += wv * __uint_as_float(rv[j].z << 16);
            ac[5] += wv * __uint_as_float(rv[j].z & 0xffff0000u);
            ac[6] += wv * __uint_as_float(rv[j].w << 16);
            ac[7] += wv * __uint_as_float(rv[j].w & 0xffff0000u);
        }
    }
    bh8 o;
#pragma unroll
    for (int i = 0; i < 8; i++) o.v[i] = __float2bfloat16(ac[i]);
    *(bh8*)(tgt2 + (size_t)q * 256 + c0) = o;
}

// ---------------------------------------------------------------------------
extern "C" void kernel_launch(void* const* d_in, const int* in_sizes, int n_in,
                              void* d_out, int out_size, void* d_ws, size_t ws_size,
                              hipStream_t stream) {
    const float* tgt     = (const float*)d_in[0];
    const float* qpos    = (const float*)d_in[1];
    const float* refp    = (const float*)d_in[2];
    const float* src     = (const float*)d_in[3];
    const float* W_value = (const float*)d_in[6];
    const float* b_value = (const float*)d_in[7];
    const float* W_off   = (const float*)d_in[8];
    const float* b_off   = (const float*)d_in[9];
    const float* W_attn  = (const float*)d_in[10];
    const float* b_attn  = (const float*)d_in[11];
    const float* W_out   = (const float*)d_in[12];
    const float* b_out   = (const float*)d_in[13];
    const float* ln1_g   = (const float*)d_in[14];
    const float* ln1_b   = (const float*)d_in[15];
    const float* W1      = (const float*)d_in[16];
    const float* b1      = (const float*)d_in[17];
    const float* W2      = (const float*)d_in[18];
    const float* b2      = (const float*)d_in[19];
    const float* ln3_g   = (const float*)d_in[20];
    const float* ln3_b   = (const float*)d_in[21];
    float* out = (float*)d_out;

    // workspace layout
    char* p = (char*)d_ws;
    auto nxt = [&](size_t b) { char* r = p; p += (b + 255) & ~(size_t)255; return r; };
    __hip_bfloat16* Wvt    = (__hip_bfloat16*)nxt((size_t)256 * 256 * 2);
    __hip_bfloat16* Woat   = (__hip_bfloat16*)nxt((size_t)384 * 256 * 2);
    __hip_bfloat16* Woutt  = (__hip_bfloat16*)nxt((size_t)256 * 256 * 2);
    __hip_bfloat16* W1t    = (__hip_bfloat16*)nxt((size_t)1024 * 256 * 2);
    __hip_bfloat16* W2t    = (__hip_bfloat16*)nxt((size_t)256 * 1024 * 2);
    __hip_bfloat16* valueb = (__hip_bfloat16*)nxt((size_t)M_V * 256 * 2);  // dead after sampler
    float*          offb   = (float*)nxt((size_t)M_Q * 256 * 4);           // dead after sampler
    float*          attnb  = (float*)nxt((size_t)M_Q * 128 * 4);
    __hip_bfloat16* tgt2b  = (__hip_bfloat16*)nxt((size_t)M_Q * 256 * 2);
    __hip_bfloat16* t2ob   = (__hip_bfloat16*)nxt((size_t)M_Q * 256 * 2);
    float*          x      = (float*)nxt((size_t)M_Q * 256 * 4);
    __hip_bfloat16* xb     = (__hip_bfloat16*)nxt((size_t)M_Q * 256 * 2);
    __hip_bfloat16* hb     = (__hip_bfloat16*)nxt((size_t)M_Q * 1024 * 2);
    // FFN2 output (f32, 16.8 MB) overlays valueb (dead after sampler)
    float* f2o = (float*)valueb;

    dim3 blk(256);

    // 0) prep: weight transpose+cvt only
    prep_kernel<<<dim3(736), blk, 0, stream>>>(
        W_value, W_off, W_attn, W_out, W1, W2,
        Wvt, Woat, Woat + 256 * 256, Woutt, W1t, W2t);

    // 1) value GEMM ++ off/attn GEMM (64x64, fused cvt, col-fastest grid)
    mfma_gemm_vq<<<dim3(6, VT64 + M_Q / 64), blk, 0, stream>>>(
        src, Wvt, b_value, valueb, tgt, qpos, Woat, b_off, b_attn, offb, attnb);

    // 2) deformable sampling -> tgt2 (bf16)
    sample_kernel<<<dim3(M_Q / QB), blk, 0, stream>>>(refp, offb, attnb, valueb, tgt2b);

    // 3) t2o = tgt2 @ W_out + b_out -> bf16  (4 x 256 = 1024 blocks)
    mfma_gemm64<256, 1><<<dim3(4, M_Q / 64), blk, 0, stream>>>(
        tgt2b, Woutt, b_out, nullptr, t2ob, 256, 256, 256);

    // 4) x = LN1(tgt + t2o) -> f32 + bf16
    ln_kernel<true><<<dim3(M_Q / 4), blk, 0, stream>>>(
        nullptr, t2ob, nullptr, tgt, nullptr, ln1_g, ln1_b, x, xb);

    // 5) h = relu(x @ W1 + b1) -> bf16  (16 x 256 = 4096 blocks)
    mfma_gemm64<256, 2><<<dim3(16, M_Q / 64), blk, 0, stream>>>(
        xb, W1t, b1, nullptr, hb, 256, 256, 1024);

    // 6) f2o = h @ W2 + b2 -> f32, K=1024 single pass  (4 x 256 blocks)
    mfma_gemm64<1024, 0><<<dim3(4, M_Q / 64), blk, 0, stream>>>(
        hb, W2t, b2, f2o, nullptr, 1024, 1024, 256);

    // 7) out = LN3(x + f2o) -> f32
    ln_kernel<false><<<dim3(M_Q / 4), blk, 0, stream>>>(
        f2o, nullptr, nullptr, x, nullptr, ln3_g, ln3_b, out, nullptr);
}

// Round 13
// 294.695 us; speedup vs baseline: 1.4201x; 1.0549x over previous
//
#include <hip/hip_runtime.h>
#include <hip/hip_bf16.h>
#include <hip/hip_fp16.h>
#include <math.h>

// Problem constants (fixed by setup_inputs)
#define D_MODEL   256
#define D_FFN     1024
#define N_LEVELS  4
#define N_HEADS   8
#define N_POINTS  4
#define BATCH     2
#define LQ        8192
#define S_TOTAL   21760            // 128*128 + 64*64 + 32*32 + 16*16
#define M_Q       (BATCH*LQ)       // 16384
#define M_V       (BATCH*S_TOTAL)  // 43520
#define VT64      (M_V/64)         // 680 row tiles for value GEMM

typedef __attribute__((ext_vector_type(8))) short bf16x8;   // 8 bf16 = 4 VGPRs
typedef __attribute__((ext_vector_type(4))) float floatx4;  // mfma C/D

struct alignas(8)  bh4 { __hip_bfloat16 a, b, c, d; };
struct alignas(16) bh8 { __hip_bfloat16 v[8]; };

__device__ __forceinline__ void gld_lds16(const void* g, void* l) {
    __builtin_amdgcn_global_load_lds(
        (const __attribute__((address_space(1))) void*)g,
        (__attribute__((address_space(3))) void*)l, 16, 0, 0);
}

__device__ __forceinline__ bh4 pack4(float4 a) {
    return { __float2bfloat16(a.x), __float2bfloat16(a.y),
             __float2bfloat16(a.z), __float2bfloat16(a.w) };
}

// ---------------------------------------------------------------------------
// 64x64 bf16 MFMA core, double-buffered LDS, one barrier/K-iter (R12: raised
// occupancy 13->37%, BW 2.4->3.3 TB/s).
// ---------------------------------------------------------------------------
template<int K>
__device__ __forceinline__ void gemm_core64(const __hip_bfloat16* __restrict__ A,
                                            const __hip_bfloat16* __restrict__ Bt,
                                            int row0, int nb0, int lda, int ldb,
                                            short* As, short* Bs, floatx4 (&acc)[4])
{
    constexpr int NIT = K / 32;
    const int tid  = threadIdx.x;
    const int w    = tid >> 6;
    const int lane = tid & 63;
    const int quad = lane >> 4;
    const int l15  = lane & 15;
    const size_t ldaB = (size_t)lda * 2, ldbB = (size_t)ldb * 2;

    const int o = w * 1024 + lane * 16;          // byte offset in 4KB tile
    const char* gA = (const char*)A + (size_t)(row0 + (o >> 6)) * ldaB + (o & 63);
    const char* gB = (const char*)Bt + (size_t)(nb0 + (o >> 6)) * ldbB + (o & 63);
    const int lofs = w * 512;                    // shorts

    gld_lds16(gA, As + lofs);
    gld_lds16(gB, Bs + lofs);

#pragma unroll 8
    for (int it = 0; it < NIT; ++it) {
        __syncthreads();
        const int cb = it & 1;
        if (it + 1 < NIT) {
            const size_t kb = (size_t)(it + 1) * 64;   // 32 k * 2 B
            gld_lds16(gA + kb, As + (cb ^ 1) * 2048 + lofs);
            gld_lds16(gB + kb, Bs + (cb ^ 1) * 2048 + lofs);
        }
        const short* Ab = As + cb * 2048;
        const short* Bb = Bs + cb * 2048;
        bf16x8 af = *(const bf16x8*)&Ab[(w * 16 + l15) * 32 + quad * 8];
#pragma unroll
        for (int ni = 0; ni < 4; ni++) {
            bf16x8 bfr = *(const bf16x8*)&Bb[(ni * 16 + l15) * 32 + quad * 8];
            acc[ni] = __builtin_amdgcn_mfma_f32_16x16x32_bf16(af, bfr, acc[ni], 0, 0, 0);
        }
    }
}

// ---------------------------------------------------------------------------
// 64x64 core with f32 A (optionally A+A2), cvt->bf16 during staging.
// Coalesced A loads (R8 lesson); sequential conflict-free 8B ds_writes.
// ---------------------------------------------------------------------------
template<int K, bool ADD>
__device__ __forceinline__ void gemm_core_cvt64(const float* __restrict__ Af,
                                                const float* __restrict__ A2f,
                                                const __hip_bfloat16* __restrict__ Bt,
                                                int row0, int nb0, int lda, int ldb,
                                                short* As, short* Bs, floatx4 (&acc)[4])
{
    constexpr int NIT = K / 32;
    const int tid  = threadIdx.x;
    const int w    = tid >> 6;
    const int lane = tid & 63;
    const int quad = lane >> 4;
    const int l15  = lane & 15;

    const int o = w * 1024 + lane * 16;
    const char* gB = (const char*)Bt + (size_t)(nb0 + (o >> 6)) * ((size_t)ldb * 2) + (o & 63);
    const int lofs = w * 512;

    const int r0 = tid >> 3, k0 = (tid & 7) * 4;     // f32 index
    const float* gA0 = Af + (size_t)(row0 + r0) * lda + k0;        // rows 0..31
    const float* gA1 = gA0 + (size_t)32 * lda;                     // rows 32..63
    const float* gB0 = ADD ? (A2f + (size_t)(row0 + r0) * lda + k0) : nullptr;
    const float* gB1 = ADD ? (gB0 + (size_t)32 * lda) : nullptr;
    const int aofs0 = r0 * 32 + k0, aofs1 = aofs0 + 1024;

    float4 f0, f1;
    auto loadA = [&](int kt) {
        f0 = *(const float4*)(gA0 + kt);
        f1 = *(const float4*)(gA1 + kt);
        if (ADD) {
            float4 a = *(const float4*)(gB0 + kt);
            float4 b = *(const float4*)(gB1 + kt);
            f0.x += a.x; f0.y += a.y; f0.z += a.z; f0.w += a.w;
            f1.x += b.x; f1.y += b.y; f1.z += b.z; f1.w += b.w;
        }
    };
    auto writeA = [&](short* buf) {
        *(bh4*)&buf[aofs0] = pack4(f0);
        *(bh4*)&buf[aofs1] = pack4(f1);
    };

    loadA(0);
    gld_lds16(gB, Bs + lofs);
    writeA(As);

#pragma unroll 8
    for (int it = 0; it < NIT; ++it) {
        __syncthreads();
        const int cb = it & 1;
        const bool more = (it + 1 < NIT);
        if (more) {
            loadA((it + 1) * 32);
            gld_lds16(gB + (size_t)(it + 1) * 64, Bs + (cb ^ 1) * 2048 + lofs);
        }
        const short* Ab = As + cb * 2048;
        const short* Bb = Bs + cb * 2048;
        bf16x8 af = *(const bf16x8*)&Ab[(w * 16 + l15) * 32 + quad * 8];
#pragma unroll
        for (int ni = 0; ni < 4; ni++) {
            bf16x8 bfr = *(const bf16x8*)&Bb[(ni * 16 + l15) * 32 + quad * 8];
            acc[ni] = __builtin_amdgcn_mfma_f32_16x16x32_bf16(af, bfr, acc[ni], 0, 0, 0);
        }
        if (more) writeA(As + (cb ^ 1) * 2048);
    }
}

// ---------------------------------------------------------------------------
// Generic 64x64 GEMM, bf16 A. 1-D grid of rows*COLS blocks with XCD-aware
// swizzle: id = g*(8*COLS) + col*8 + rowlane, so the COLS blocks sharing an
// A row-tile all have id = rowlane (mod 8) -> SAME XCD (round-robin CP
// dispatch) -> A fetched from HBM once into that XCD's L2.
// R12 measured the failure mode this fixes: col-adjacent ids -> 4 XCDs ->
// FETCH_SIZE doubled (187 MB, src read 4x). Per-XCD L2s are not coherent.
// EPI: 0 f32 (+bias); 1 bf16 (+bias); 2 relu -> bf16.
// ---------------------------------------------------------------------------
template<int K, int EPI, int COLS>
__global__ __launch_bounds__(256)
void mfma_gemm64(const __hip_bfloat16* __restrict__ A,
                 const __hip_bfloat16* __restrict__ Bt,
                 const float* __restrict__ bias,
                 float* __restrict__ outf, __hip_bfloat16* __restrict__ outb,
                 int lda, int ldb, int ldOut)
{
    __shared__ alignas(16) short As[2 * 2048];
    __shared__ alignas(16) short Bs[2 * 2048];

    constexpr int BPG = 8 * COLS;
    const int g  = blockIdx.x / BPG;
    const int wq = blockIdx.x % BPG;
    const int row0 = (g * 8 + (wq & 7)) * 64;
    const int nb0  = (wq >> 3) * 64;

    const int tid = threadIdx.x, w = tid >> 6, lane = tid & 63;
    const int quad = lane >> 4, l15 = lane & 15;

    floatx4 acc[4];
#pragma unroll
    for (int ni = 0; ni < 4; ni++) acc[ni] = (floatx4){0.f, 0.f, 0.f, 0.f};

    gemm_core64<K>(A, Bt, row0, nb0, lda, ldb, As, Bs, acc);

    float bias_c[4];
#pragma unroll
    for (int ni = 0; ni < 4; ni++) bias_c[ni] = bias ? bias[nb0 + ni * 16 + l15] : 0.f;

#pragma unroll
    for (int r = 0; r < 4; r++) {
        int row = row0 + w * 16 + quad * 4 + r;
        size_t rb = (size_t)row * ldOut + nb0;
#pragma unroll
        for (int ni = 0; ni < 4; ni++) {
            float v = acc[ni][r] + bias_c[ni];
            if (EPI == 2)      outb[rb + ni * 16 + l15] = __float2bfloat16(fmaxf(v, 0.f));
            else if (EPI == 1) outb[rb + ni * 16 + l15] = __float2bfloat16(v);
            else               outf[rb + ni * 16 + l15] = v;
        }
    }
}

// ---------------------------------------------------------------------------
// Merged value-projection + off/attn GEMM (64x64, fused f32 cvt staging),
// 1-D grid with the same XCD-aware swizzle.
// ids [0, 2720): value part — groups of 32 = 8 rows x 4 cols.
// ids [2720, 4256): off/attn — groups of 48 = 8 rows x 6 cols
//   (col<4 -> off cols c*64, f32 ld 256; col>=4 -> attn, softmax16, ld 128).
// 2720 % 8 == 0 so the mod-8 invariant holds in both parts.
// ---------------------------------------------------------------------------
__global__ __launch_bounds__(256)
void mfma_gemm_vq(const float* __restrict__ src,
                  const __hip_bfloat16* __restrict__ Wvt,
                  const float* __restrict__ b_value,
                  __hip_bfloat16* __restrict__ valueb,
                  const float* __restrict__ tgt, const float* __restrict__ qpos,
                  const __hip_bfloat16* __restrict__ Woat,
                  const float* __restrict__ b_off, const float* __restrict__ b_attn,
                  float* __restrict__ offb, float* __restrict__ attnb)
{
    __shared__ alignas(16) short As[2 * 2048];
    __shared__ alignas(16) short Bs[2 * 2048];

    const int id = blockIdx.x;
    const int tid = threadIdx.x, w = tid >> 6, lane = tid & 63;
    const int quad = lane >> 4, l15 = lane & 15;

    floatx4 acc[4];
#pragma unroll
    for (int ni = 0; ni < 4; ni++) acc[ni] = (floatx4){0.f, 0.f, 0.f, 0.f};

    if (id < VT64 * 4) {     // value part
        const int g = id >> 5, wq = id & 31;
        const int row0 = (g * 8 + (wq & 7)) * 64;
        const int nb0  = (wq >> 3) * 64;
        gemm_core_cvt64<256, false>(src, nullptr, Wvt, row0, nb0, 256, 256, As, Bs, acc);
        float bias_c[4];
#pragma unroll
        for (int ni = 0; ni < 4; ni++) bias_c[ni] = b_value[nb0 + ni * 16 + l15];
#pragma unroll
        for (int r = 0; r < 4; r++) {
            int row = row0 + w * 16 + quad * 4 + r;
            size_t rb = (size_t)row * 256 + nb0;
#pragma unroll
            for (int ni = 0; ni < 4; ni++)
                valueb[rb + ni * 16 + l15] = __float2bfloat16(acc[ni][r] + bias_c[ni]);
        }
        return;
    }

    const int oid = id - VT64 * 4;
    const int g = oid / 48, wq = oid % 48;
    const int row0 = (g * 8 + (wq & 7)) * 64;
    const int c = wq >> 3;   // 0..5

    if (c < 4) {             // offsets: cols c*64 of Woat, f32 out ld 256
        const int nb0 = c * 64;
        gemm_core_cvt64<256, true>(tgt, qpos, Woat, row0, nb0, 256, 256, As, Bs, acc);
        float bias_c[4];
#pragma unroll
        for (int ni = 0; ni < 4; ni++) bias_c[ni] = b_off[nb0 + ni * 16 + l15];
#pragma unroll
        for (int r = 0; r < 4; r++) {
            int row = row0 + w * 16 + quad * 4 + r;
            size_t rb = (size_t)row * 256 + nb0;
#pragma unroll
            for (int ni = 0; ni < 4; ni++)
                offb[rb + ni * 16 + l15] = acc[ni][r] + bias_c[ni];
        }
    } else {                 // attn: Woat rows 256 + (c-4)*64; softmax16
        const int c0 = (c - 4) * 64;
        gemm_core_cvt64<256, true>(tgt, qpos, Woat, row0, 256 + c0, 256, 256, As, Bs, acc);
        float bias_c[4];
#pragma unroll
        for (int ni = 0; ni < 4; ni++) bias_c[ni] = b_attn[c0 + ni * 16 + l15];
#pragma unroll
        for (int r = 0; r < 4; r++) {
            int row = row0 + w * 16 + quad * 4 + r;
            size_t rb = (size_t)row * 128 + c0;
#pragma unroll
            for (int ni = 0; ni < 4; ni++) {
                float v = acc[ni][r] + bias_c[ni];
                float m = v;
#pragma unroll
                for (int msk = 1; msk <= 8; msk <<= 1) m = fmaxf(m, __shfl_xor(m, msk));
                float e = __expf(v - m);
                float ssum = e;
#pragma unroll
                for (int msk = 1; msk <= 8; msk <<= 1) ssum += __shfl_xor(ssum, msk);
                attnb[rb + ni * 16 + l15] = e / ssum;
            }
        }
    }
}

// ---------------------------------------------------------------------------
// Residual + LayerNorm, one wave per 256-col row.
// v = resid + in1 (+ in2) (+ bias). B1: in1 is bf16.
// ---------------------------------------------------------------------------
template<bool B1>
__global__ __launch_bounds__(256)
void ln_kernel(const float* __restrict__ in1f, const __hip_bfloat16* __restrict__ in1b,
               const float* __restrict__ in2,
               const float* __restrict__ resid, const float* __restrict__ bias,
               const float* __restrict__ g, const float* __restrict__ b,
               float* __restrict__ outf, __hip_bfloat16* __restrict__ outb)
{
    const int row  = blockIdx.x * 4 + (threadIdx.x >> 6);
    const int lane = threadIdx.x & 63;
    const size_t rb = (size_t)row * 256 + lane * 4;

    float4 v = *(const float4*)(resid + rb);
    if (B1) {
        bh4 a = *(const bh4*)(in1b + rb);
        v.x += __bfloat162float(a.a); v.y += __bfloat162float(a.b);
        v.z += __bfloat162float(a.c); v.w += __bfloat162float(a.d);
    } else {
        float4 a = *(const float4*)(in1f + rb);
        v.x += a.x; v.y += a.y; v.z += a.z; v.w += a.w;
    }
    if (in2) {
        float4 c = *(const float4*)(in2 + rb);
        v.x += c.x; v.y += c.y; v.z += c.z; v.w += c.w;
    }
    if (bias) {
        float4 c = *(const float4*)(bias + lane * 4);
        v.x += c.x; v.y += c.y; v.z += c.z; v.w += c.w;
    }
    float s  = v.x + v.y + v.z + v.w;
    float sq = v.x * v.x + v.y * v.y + v.z * v.z + v.w * v.w;
#pragma unroll
    for (int msk = 1; msk <= 32; msk <<= 1) {
        s += __shfl_xor(s, msk); sq += __shfl_xor(sq, msk);
    }
    float mean = s * (1.f / 256.f);
    float var  = sq * (1.f / 256.f) - mean * mean;
    float rstd = rsqrtf(var + 1e-5f);
    float4 gg = *(const float4*)(g + lane * 4);
    float4 bb = *(const float4*)(b + lane * 4);
    float4 o;
    o.x = (v.x - mean) * rstd * gg.x + bb.x;
    o.y = (v.y - mean) * rstd * gg.y + bb.y;
    o.z = (v.z - mean) * rstd * gg.z + bb.z;
    o.w = (v.w - mean) * rstd * gg.w + bb.w;
    *(float4*)(outf + rb) = o;
    if (outb)
        *(bh4*)(outb + rb) = { __float2bfloat16(o.x), __float2bfloat16(o.y),
                               __float2bfloat16(o.z), __float2bfloat16(o.w) };
}

// ---------------------------------------------------------------------------
// Prep: weight transpose + f32->bf16 only (736 tiles of 32x32)
// ---------------------------------------------------------------------------
__global__ __launch_bounds__(256)
void prep_kernel(const float* w0, const float* w1, const float* w2,
                 const float* w3, const float* w4, const float* w5,
                 __hip_bfloat16* o0, __hip_bfloat16* o1, __hip_bfloat16* o2,
                 __hip_bfloat16* o3, __hip_bfloat16* o4, __hip_bfloat16* o5)
{
    int t = blockIdx.x;
    const float* s; __hip_bfloat16* dst; int Kd, Nd, tl;
    if      (t < 64)  { s = w0; dst = o0; Kd = 256;  Nd = 256;  tl = t; }
    else if (t < 128) { s = w1; dst = o1; Kd = 256;  Nd = 256;  tl = t - 64; }
    else if (t < 160) { s = w2; dst = o2; Kd = 256;  Nd = 128;  tl = t - 128; }
    else if (t < 224) { s = w3; dst = o3; Kd = 256;  Nd = 256;  tl = t - 160; }
    else if (t < 480) { s = w4; dst = o4; Kd = 256;  Nd = 1024; tl = t - 224; }
    else              { s = w5; dst = o5; Kd = 1024; Nd = 256;  tl = t - 480; }
    int ntn = Nd >> 5;
    int kt = tl / ntn, nt = tl - kt * ntn;
    __shared__ float T[32][33];
    int tx = threadIdx.x & 31, ty = threadIdx.x >> 5;
#pragma unroll
    for (int i = 0; i < 4; i++) {
        int k = kt * 32 + ty + i * 8;
        T[tx][ty + i * 8] = s[(size_t)k * Nd + nt * 32 + tx];
    }
    __syncthreads();
#pragma unroll
    for (int i = 0; i < 4; i++) {
        int n = nt * 32 + ty + i * 8;
        dst[(size_t)n * Kd + kt * 32 + tx] = __float2bfloat16(T[ty + i * 8][tx]);
    }
}

// ---------------------------------------------------------------------------
// Deformable bilinear sampling (R8 version, 44.7 us best). Block = 8 queries,
// LDS 4B/entry, stride-65, 16-deep batched 16B gathers.
// ---------------------------------------------------------------------------
#define QB 8
__global__ __launch_bounds__(256, 4)
void sample_kernel(const float* __restrict__ refp, const float* __restrict__ offb,
                   const float* __restrict__ attn,
                   const __hip_bfloat16* __restrict__ value,
                   __hip_bfloat16* __restrict__ tgt2)
{
    __shared__ unsigned spk[64 * 65];       // [sc=lp*4+c][g=ql*8+h]

    const int q0  = blockIdx.x * QB;
    const int tid = threadIdx.x;

#pragma unroll
    for (int k = 0; k < 4; k++) {
        const int it = tid + k * 256;        // (ql,h,lp)
        const int ql = it >> 7, h = (it >> 4) & 7, lp = it & 15;
        const int l = lp >> 2, p = lp & 3;
        const int q = q0 + ql, b = q >> 13;
        const int Wl = 128 >> l;
        const int LST = (l == 0) ? 0 : (l == 1) ? 16384 : (l == 2) ? 20480 : 21504;

        const float rx = refp[((size_t)q * N_LEVELS + l) * 2 + 0];
        const float ry = refp[((size_t)q * N_LEVELS + l) * 2 + 1];
        const float ox = offb[(size_t)q * 256 + h * 32 + l * 8 + p * 2 + 0];
        const float oy = offb[(size_t)q * 256 + h * 32 + l * 8 + p * 2 + 1];
        const float a  = attn[(size_t)q * 128 + h * 16 + lp];

        const float x = rx * Wl - 0.5f + ox;
        const float y = ry * Wl - 0.5f + oy;
        const float x0f = floorf(x), y0f = floorf(y);
        const float wx = x - x0f, wy = y - y0f;
        const int ix = (int)x0f, iy = (int)y0f;
        const int base = b * S_TOTAL + LST;
        const int g = ql * 8 + h;
        const float cw[4] = {(1.f - wx) * (1.f - wy) * a, wx * (1.f - wy) * a,
                             (1.f - wx) * wy * a,         wx * wy * a};
#pragma unroll
        for (int c = 0; c < 4; c++) {
            const int xi = ix + (c & 1), yi = iy + (c >> 1);
            const bool valid = ((unsigned)xi < (unsigned)Wl) && ((unsigned)yi < (unsigned)Wl);
            const unsigned pix = valid ? (unsigned)(base + yi * Wl + xi) : (unsigned)base;
            const __half hw = __float2half(valid ? cw[c] : 0.f);
            spk[(lp * 4 + c) * 65 + g] = (pix << 16) | (unsigned)__half_as_ushort(hw);
        }
    }
    __syncthreads();

    const int ql = tid >> 5, h = (tid >> 2) & 7, d4 = tid & 3;
    const int q = q0 + ql, g = ql * 8 + h;
    const int c0 = h * 32 + d4 * 8;
    const char* vb = (const char*)value + (size_t)c0 * 2;

    float ac[8] = {0.f, 0.f, 0.f, 0.f, 0.f, 0.f, 0.f, 0.f};
#pragma unroll
    for (int ch = 0; ch < 4; ch++) {
        unsigned us[16];
#pragma unroll
        for (int j = 0; j < 16; j++) us[j] = spk[(ch * 16 + j) * 65 + g];
        uint4 rv[16];
#pragma unroll
        for (int j = 0; j < 16; j++)
            rv[j] = *(const uint4*)(vb + ((size_t)(us[j] >> 16) << 9));
#pragma unroll
        for (int j = 0; j < 16; j++) {
            float wv = __half2float(__ushort_as_half((unsigned short)(us[j] & 0xffffu)));
            ac[0] += wv * __uint_as_float(rv[j].x << 16);
            ac[1] += wv * __uint_as_float(rv[j].x & 0xffff0000u);
            ac[2] += wv * __uint_as_float(rv[j].y << 16);
            ac[3] += wv * __uint_as_float(rv[j].y & 0xffff0000u);
            ac[4] += wv * __uint_as_float(rv[j].z << 16);
            ac[5] += wv * __uint_as_float(rv[j].z & 0xffff0000u);
            ac[6] += wv * __uint_as_float(rv[j].w << 16);
            ac[7] += wv * __uint_as_float(rv[j].w & 0xffff0000u);
        }
    }
    bh8 o;
#pragma unroll
    for (int i = 0; i < 8; i++) o.v[i] = __float2bfloat16(ac[i]);
    *(bh8*)(tgt2 + (size_t)q * 256 + c0) = o;
}

// ---------------------------------------------------------------------------
extern "C" void kernel_launch(void* const* d_in, const int* in_sizes, int n_in,
                              void* d_out, int out_size, void* d_ws, size_t ws_size,
                              hipStream_t stream) {
    const float* tgt     = (const float*)d_in[0];
    const float* qpos    = (const float*)d_in[1];
    const float* refp    = (const float*)d_in[2];
    const float* src     = (const float*)d_in[3];
    const float* W_value = (const float*)d_in[6];
    const float* b_value = (const float*)d_in[7];
    const float* W_off   = (const float*)d_in[8];
    const float* b_off   = (const float*)d_in[9];
    const float* W_attn  = (const float*)d_in[10];
    const float* b_attn  = (const float*)d_in[11];
    const float* W_out   = (const float*)d_in[12];
    const float* b_out   = (const float*)d_in[13];
    const float* ln1_g   = (const float*)d_in[14];
    const float* ln1_b   = (const float*)d_in[15];
    const float* W1      = (const float*)d_in[16];
    const float* b1      = (const float*)d_in[17];
    const float* W2      = (const float*)d_in[18];
    const float* b2      = (const float*)d_in[19];
    const float* ln3_g   = (const float*)d_in[20];
    const float* ln3_b   = (const float*)d_in[21];
    float* out = (float*)d_out;

    // workspace layout
    char* p = (char*)d_ws;
    auto nxt = [&](size_t b) { char* r = p; p += (b + 255) & ~(size_t)255; return r; };
    __hip_bfloat16* Wvt    = (__hip_bfloat16*)nxt((size_t)256 * 256 * 2);
    __hip_bfloat16* Woat   = (__hip_bfloat16*)nxt((size_t)384 * 256 * 2);
    __hip_bfloat16* Woutt  = (__hip_bfloat16*)nxt((size_t)256 * 256 * 2);
    __hip_bfloat16* W1t    = (__hip_bfloat16*)nxt((size_t)1024 * 256 * 2);
    __hip_bfloat16* W2t    = (__hip_bfloat16*)nxt((size_t)256 * 1024 * 2);
    __hip_bfloat16* valueb = (__hip_bfloat16*)nxt((size_t)M_V * 256 * 2);  // dead after sampler
    float*          offb   = (float*)nxt((size_t)M_Q * 256 * 4);           // dead after sampler
    float*          attnb  = (float*)nxt((size_t)M_Q * 128 * 4);
    __hip_bfloat16* tgt2b  = (__hip_bfloat16*)nxt((size_t)M_Q * 256 * 2);
    __hip_bfloat16* t2ob   = (__hip_bfloat16*)nxt((size_t)M_Q * 256 * 2);
    float*          x      = (float*)nxt((size_t)M_Q * 256 * 4);
    __hip_bfloat16* xb     = (__hip_bfloat16*)nxt((size_t)M_Q * 256 * 2);
    __hip_bfloat16* hb     = (__hip_bfloat16*)nxt((size_t)M_Q * 1024 * 2);
    // FFN2 output (f32, 16.8 MB) overlays valueb (dead after sampler)
    float* f2o = (float*)valueb;

    dim3 blk(256);

    // 0) prep: weight transpose+cvt only
    prep_kernel<<<dim3(736), blk, 0, stream>>>(
        W_value, W_off, W_attn, W_out, W1, W2,
        Wvt, Woat, Woat + 256 * 256, Woutt, W1t, W2t);

    // 1) value GEMM ++ off/attn GEMM (64x64, fused cvt, XCD swizzle)
    mfma_gemm_vq<<<dim3(VT64 * 4 + 256 / 8 * 48), blk, 0, stream>>>(
        src, Wvt, b_value, valueb, tgt, qpos, Woat, b_off, b_attn, offb, attnb);

    // 2) deformable sampling -> tgt2 (bf16)
    sample_kernel<<<dim3(M_Q / QB), blk, 0, stream>>>(refp, offb, attnb, valueb, tgt2b);

    // 3) t2o = tgt2 @ W_out + b_out -> bf16  (COLS=4, 1024 blocks)
    mfma_gemm64<256, 1, 4><<<dim3(M_Q / 64 * 4), blk, 0, stream>>>(
        tgt2b, Woutt, b_out, nullptr, t2ob, 256, 256, 256);

    // 4) x = LN1(tgt + t2o) -> f32 + bf16
    ln_kernel<true><<<dim3(M_Q / 4), blk, 0, stream>>>(
        nullptr, t2ob, nullptr, tgt, nullptr, ln1_g, ln1_b, x, xb);

    // 5) h = relu(x @ W1 + b1) -> bf16  (COLS=16, 4096 blocks)
    mfma_gemm64<256, 2, 16><<<dim3(M_Q / 64 * 16), blk, 0, stream>>>(
        xb, W1t, b1, nullptr, hb, 256, 256, 1024);

    // 6) f2o = h @ W2 + b2 -> f32, K=1024  (COLS=4, 1024 blocks)
    mfma_gemm64<1024, 0, 4><<<dim3(M_Q / 64 * 4), blk, 0, stream>>>(
        hb, W2t, b2, f2o, nullptr, 1024, 1024, 256);

    // 7) out = LN3(x + f2o) -> f32
    ln_kernel<false><<<dim3(M_Q / 4), blk, 0, stream>>>(
        f2o, nullptr, nullptr, x, nullptr, ln3_g, ln3_b, out, nullptr);
}